// Round 20
// baseline (292.711 us; speedup 1.0000x reference)
//
#include <hip/hip_runtime.h>
#include <hip/hip_bf16.h>
#include <math.h>

#define B_   2
#define T_   2048
#define C_   1024
#define H_   16
#define D_   64
#define NCH  32
#define RD   32
#define TOPB 8

typedef __attribute__((ext_vector_type(8))) short bf16x8;
typedef __attribute__((ext_vector_type(4))) float f32x4;

static __device__ __forceinline__ unsigned short f2b(float f) {
    return __bfloat16_as_ushort(__float2bfloat16(f));
}
static __device__ __forceinline__ float b2f(unsigned short u) {
    union { unsigned u32; float f; } c; c.u32 = ((unsigned)u) << 16; return c.f;
}

#define SCALE2 0.18033688f   /* 0.125 * 1.44269504 (log2 domain) */

// ---------------------------------------------------------------------------
// prep_fused v2 (2304 blocks):
//   [0,768)       Wqkv [K][3072] -> Wqt bf16 [3072][K]
//   [768,1024)    Wproj -> Wpt
//   [1024,2048)   qrt = l2norm(x @ Wq_rt + b)
//   [2048,2304)   chunk means + x->bf16 cast fused (single pass over x)
// ---------------------------------------------------------------------------
__global__ __launch_bounds__(256) void prep_fused(
    const float* __restrict__ x, unsigned short* __restrict__ xb,
    const float* __restrict__ Wqkv, unsigned short* __restrict__ Wqt,
    const float* __restrict__ Wproj, unsigned short* __restrict__ Wpt,
    const float* __restrict__ Wq_rt, const float* __restrict__ bq_rt,
    float* __restrict__ qrt, float* __restrict__ cm)
{
    __shared__ float smem[64 * 65];
    const int bid = blockIdx.x;
    const int tid = threadIdx.x;

    if (bid < 1024) {                      // ---- weight transpose+cast
        const float* W; unsigned short* Wt; int N, local;
        if (bid < 768) { W = Wqkv;  Wt = Wqt; N = 3072; local = bid; }
        else           { W = Wproj; Wt = Wpt; N = 1024; local = bid - 768; }
        const int nblk = N >> 6;
        const int n0 = (local % nblk) * 64, k0 = (local / nblk) * 64;
        float (*t)[65] = (float(*)[65])smem;
#pragma unroll
        for (int i = 0; i < 4; i++) {
            const int f = tid + i * 256;
            const int r = f >> 4, c4 = (f & 15) * 4;
            float4 v = *(const float4*)&W[(size_t)(k0 + r) * N + n0 + c4];
            t[r][c4 + 0] = v.x; t[r][c4 + 1] = v.y;
            t[r][c4 + 2] = v.z; t[r][c4 + 3] = v.w;
        }
        __syncthreads();
#pragma unroll
        for (int i = 0; i < 2; i++) {
            const int s = tid + i * 256;
            const int rn = s >> 3, ck8 = (s & 7) * 8;
            bf16x8 o;
#pragma unroll
            for (int j = 0; j < 8; j++) o[j] = (short)f2b(t[ck8 + j][rn]);
            *(bf16x8*)&Wt[(size_t)(n0 + rn) * 1024 + k0 + ck8] = o;
        }
    } else if (bid < 2048) {               // ---- qrt projection + l2norm
        float (*part)[4][32] = (float(*)[4][32])smem;
        const int r0 = (bid - 1024) * 4;
        const int g = tid >> 5;
        const int n = tid & 31;
        const float* w  = Wq_rt + (size_t)(g * 128) * RD + n;
        const float* a0 = x + (size_t)(r0 + 0) * C_ + g * 128;
        const float* a1 = x + (size_t)(r0 + 1) * C_ + g * 128;
        const float* a2 = x + (size_t)(r0 + 2) * C_ + g * 128;
        const float* a3 = x + (size_t)(r0 + 3) * C_ + g * 128;
        float acc0 = 0.f, acc1 = 0.f, acc2 = 0.f, acc3 = 0.f;
#pragma unroll 8
        for (int i = 0; i < 128; i += 4) {
            const float w0 = w[(i + 0) * RD];
            const float w1 = w[(i + 1) * RD];
            const float w2 = w[(i + 2) * RD];
            const float w3 = w[(i + 3) * RD];
            float4 x0 = *(const float4*)&a0[i];
            float4 x1 = *(const float4*)&a1[i];
            float4 x2 = *(const float4*)&a2[i];
            float4 x3 = *(const float4*)&a3[i];
            acc0 += x0.x * w0; acc0 += x0.y * w1; acc0 += x0.z * w2; acc0 += x0.w * w3;
            acc1 += x1.x * w0; acc1 += x1.y * w1; acc1 += x1.z * w2; acc1 += x1.w * w3;
            acc2 += x2.x * w0; acc2 += x2.y * w1; acc2 += x2.z * w2; acc2 += x2.w * w3;
            acc3 += x3.x * w0; acc3 += x3.y * w1; acc3 += x3.z * w2; acc3 += x3.w * w3;
        }
        part[g][0][n] = acc0;
        part[g][1][n] = acc1;
        part[g][2][n] = acc2;
        part[g][3][n] = acc3;
        __syncthreads();
        if (g < 4) {
            float s = part[0][g][n];
#pragma unroll
            for (int gg = 1; gg < 8; gg++) s += part[gg][g][n];
            s += bq_rt[n];
            float ss = s * s;
#pragma unroll
            for (int off = 16; off >= 1; off >>= 1) ss += __shfl_xor(ss, off, 32);
            qrt[(size_t)(r0 + g) * RD + n] = s / fmaxf(sqrtf(ss), 1e-12f);
        }
    } else {                               // ---- chunk means + x->bf16 cast
        const int local = bid - 2048;      // 0..255
        const int bc = local & 63;
        const int b = bc >> 5, n = bc & 31;
        const int c = (local >> 6) * 256 + tid;
        const size_t rowbase = ((size_t)b * T_ + n * 64) * C_ + c;
        float s = 0.f;
        for (int i = 0; i < 64; i++) {
            const float v = x[rowbase + (size_t)i * C_];
            s += v;
            xb[rowbase + (size_t)i * C_] = f2b(v);
        }
        cm[(size_t)bc * C_ + c] = s * (1.0f / 64.0f);
    }
}

// ---------------------------------------------------------------------------
// routing embeds + l2norm fused
// ---------------------------------------------------------------------------
__global__ void embeds_kernel(const float* __restrict__ cm, const float* __restrict__ W,
                              const float* __restrict__ bias,
                              float* __restrict__ emb_out, float* __restrict__ ren)
{
    const int row  = blockIdx.x * 8 + (threadIdx.x >> 5);
    const int lane = threadIdx.x & 31;
    if (row >= B_ * NCH) return;
    const float* a = cm + (size_t)row * C_;
    float acc = 0.f;
    for (int k = 0; k < C_; k += 4) {
        float4 a4 = *(const float4*)&a[k];
        acc += a4.x * W[(k + 0) * RD + lane];
        acc += a4.y * W[(k + 1) * RD + lane];
        acc += a4.z * W[(k + 2) * RD + lane];
        acc += a4.w * W[(k + 3) * RD + lane];
    }
    acc += bias[lane];
    emb_out[(size_t)row * RD + lane] = acc;
    float ss = acc * acc;
#pragma unroll
    for (int off = 16; off >= 1; off >>= 1) ss += __shfl_xor(ss, off, 32);
    ren[(size_t)row * RD + lane] = acc / fmaxf(sqrtf(ss), 1e-12f);
}

// ---------------------------------------------------------------------------
// qkv GEMM, 128x256 tile, 8 waves, tri-buffered + counted vmcnt (R14)
// ---------------------------------------------------------------------------
__global__ __launch_bounds__(512, 4) void gemm_qkv_128x256(
    const unsigned short* __restrict__ A, const unsigned short* __restrict__ Bt,
    const float* __restrict__ bias,
    unsigned short* __restrict__ qp, unsigned short* __restrict__ kp,
    unsigned short* __restrict__ vp, int M, int N, int K)
{
    __shared__ unsigned short lds[3][12288];

    const int tid  = threadIdx.x;
    const int wid  = tid >> 6;
    const int lane = tid & 63;
    const int lr = lane & 15, lg = lane >> 4;
    const int wm = wid >> 2;
    const int wn = wid & 3;

    const int bid = blockIdx.x;
    const int swz = (bid & 7) * 48 + (bid >> 3);
    const int m0 = (swz & 31) << 7;
    const int n0 = (swz >> 5) << 8;

    const int srow = tid >> 2;
    const int sswz = (((srow & 3) ^ ((srow >> 2) & 3)) << 4);
    const int skel = (((tid & 3) << 4) ^ sswz) >> 1;
    const unsigned short* gA  = A  + (size_t)(m0 + srow) * K + skel;
    const unsigned short* gB0 = Bt + (size_t)(n0 + srow) * K + skel;
    const unsigned short* gB1 = Bt + (size_t)(n0 + srow + 128) * K + skel;
    const int lb = wid * 512;

#define QSTAGE(sl, kofs)                                                          \
    __builtin_amdgcn_global_load_lds(                                             \
        (const __attribute__((address_space(1))) int*)(gA + (kofs)),              \
        (__attribute__((address_space(3))) int*)&lds[sl][lb], 16, 0, 0);          \
    __builtin_amdgcn_global_load_lds(                                             \
        (const __attribute__((address_space(1))) int*)(gB0 + (kofs)),             \
        (__attribute__((address_space(3))) int*)&lds[sl][4096 + lb], 16, 0, 0);   \
    __builtin_amdgcn_global_load_lds(                                             \
        (const __attribute__((address_space(1))) int*)(gB1 + (kofs)),             \
        (__attribute__((address_space(3))) int*)&lds[sl][8192 + lb], 16, 0, 0);

    const int rswz = (((lr & 3) ^ ((lr >> 2) & 3)) << 4);
    const int acol = (((lg << 4) ^ rswz) >> 1);

    f32x4 acc[4][4];
#pragma unroll
    for (int i = 0; i < 4; i++)
#pragma unroll
        for (int j = 0; j < 4; j++) acc[i][j] = (f32x4){0.f, 0.f, 0.f, 0.f};

    const int nt = K >> 5;

    QSTAGE(0, 0)
    QSTAGE(1, 32)
    asm volatile("s_waitcnt vmcnt(3)" ::: "memory");
    __builtin_amdgcn_s_barrier();

    int cur = 0;
    for (int t = 0; t < nt; ++t) {
        int s2 = cur + 2; if (s2 >= 3) s2 -= 3;
        if (t + 2 < nt) { QSTAGE(s2, (t + 2) << 5) }

        const unsigned short* sA = &lds[cur][0];
        const unsigned short* sB = &lds[cur][4096];

        bf16x8 af[4], bfr[4];
#pragma unroll
        for (int mi = 0; mi < 4; mi++)
            af[mi] = *(const bf16x8*)&sA[(wm * 64 + mi * 16 + lr) * 32 + acol];
#pragma unroll
        for (int ni = 0; ni < 4; ni++)
            bfr[ni] = *(const bf16x8*)&sB[(wn * 64 + ni * 16 + lr) * 32 + acol];

        __builtin_amdgcn_s_setprio(1);
#pragma unroll
        for (int mi = 0; mi < 4; mi++)
#pragma unroll
            for (int ni = 0; ni < 4; ni++)
                acc[mi][ni] = __builtin_amdgcn_mfma_f32_16x16x32_bf16(
                    af[mi], bfr[ni], acc[mi][ni], 0, 0, 0);
        __builtin_amdgcn_s_setprio(0);

        if (t + 1 < nt) {
            if (t + 2 < nt) { asm volatile("s_waitcnt vmcnt(3)" ::: "memory"); }
            else            { asm volatile("s_waitcnt vmcnt(0)" ::: "memory"); }
            __builtin_amdgcn_s_barrier();
        }
        cur += 1; if (cur == 3) cur = 0;
    }
#undef QSTAGE

#pragma unroll
    for (int ni = 0; ni < 4; ni++) {
        const int col = n0 + wn * 64 + ni * 16 + lr;
        const float bv = bias[col];
        const int which = col >> 10;
        const int c  = col & 1023;
        const int hh = c >> 6;
        const int dd = c & 63;
        unsigned short* dst = (which == 0) ? qp : (which == 1) ? kp : vp;
        const float postmul = (which == 0) ? SCALE2 : 1.0f;
#pragma unroll
        for (int mi = 0; mi < 4; mi++) {
#pragma unroll
            for (int r = 0; r < 4; r++) {
                const int row = m0 + wm * 64 + mi * 16 + lg * 4 + r;
                const int bb = row >> 11, tt = row & 2047;
                dst[(((size_t)bb * H_ + hh) * T_ + tt) * D_ + dd] =
                    f2b((acc[mi][ni][r] + bv) * postmul);
            }
        }
    }
}

// ---------------------------------------------------------------------------
// proj GEMM, 128x128 tile, tri-buffered + counted vmcnt + swizzle (R12)
// ---------------------------------------------------------------------------
__global__ __launch_bounds__(256, 1) void gemm_proj_128(
    const unsigned short* __restrict__ A, const unsigned short* __restrict__ Bt,
    const float* __restrict__ bias, float* __restrict__ out, int M, int N, int K)
{
    __shared__ unsigned short lds[3][2][4096];

    const int tid  = threadIdx.x;
    const int lane = tid & 63;
    const int wave = tid >> 6;
    const int lr = lane & 15, lg = lane >> 4;
    const int wm = wave >> 1, wn = wave & 1;
    const int n0 = blockIdx.x * 128, m0 = blockIdx.y * 128;

    const int srow = tid >> 2;
    const int sswz = (((srow & 3) ^ ((srow >> 2) & 3)) << 4);
    const int skel = (((tid & 3) << 4) ^ sswz) >> 1;
    const unsigned short* gA0 = A  + (size_t)(m0 + srow) * K + skel;
    const unsigned short* gA1 = A  + (size_t)(m0 + srow + 64) * K + skel;
    const unsigned short* gB0 = Bt + (size_t)(n0 + srow) * K + skel;
    const unsigned short* gB1 = Bt + (size_t)(n0 + srow + 64) * K + skel;
    const int ldb = (tid & 0xC0) * 8;

#define PSTAGE(sl, kofs)                                                          \
    __builtin_amdgcn_global_load_lds(                                             \
        (const __attribute__((address_space(1))) int*)(gA0 + (kofs)),             \
        (__attribute__((address_space(3))) int*)&lds[sl][0][ldb], 16, 0, 0);      \
    __builtin_amdgcn_global_load_lds(                                             \
        (const __attribute__((address_space(1))) int*)(gA1 + (kofs)),             \
        (__attribute__((address_space(3))) int*)&lds[sl][0][2048 + ldb], 16, 0, 0); \
    __builtin_amdgcn_global_load_lds(                                             \
        (const __attribute__((address_space(1))) int*)(gB0 + (kofs)),             \
        (__attribute__((address_space(3))) int*)&lds[sl][1][ldb], 16, 0, 0);      \
    __builtin_amdgcn_global_load_lds(                                             \
        (const __attribute__((address_space(1))) int*)(gB1 + (kofs)),             \
        (__attribute__((address_space(3))) int*)&lds[sl][1][2048 + ldb], 16, 0, 0);

    const int rswz = (((lr & 3) ^ ((lr >> 2) & 3)) << 4);
    const int acol = (((lg << 4) ^ rswz) >> 1);

    f32x4 acc[4][4];
#pragma unroll
    for (int i = 0; i < 4; i++)
#pragma unroll
        for (int j = 0; j < 4; j++) acc[i][j] = (f32x4){0.f, 0.f, 0.f, 0.f};

    const int nt = K >> 5;

    PSTAGE(0, 0)
    PSTAGE(1, 32)
    asm volatile("s_waitcnt vmcnt(4)" ::: "memory");
    __builtin_amdgcn_s_barrier();

    int cur = 0;
    for (int t = 0; t < nt; ++t) {
        int s2 = cur + 2; if (s2 >= 3) s2 -= 3;
        if (t + 2 < nt) { PSTAGE(s2, (t + 2) << 5) }

        const unsigned short* sA = &lds[cur][0][0];
        const unsigned short* sB = &lds[cur][1][0];

        bf16x8 af[4], bfr[4];
#pragma unroll
        for (int mi = 0; mi < 4; mi++)
            af[mi] = *(const bf16x8*)&sA[(wm * 64 + mi * 16 + lr) * 32 + acol];
#pragma unroll
        for (int ni = 0; ni < 4; ni++)
            bfr[ni] = *(const bf16x8*)&sB[(wn * 64 + ni * 16 + lr) * 32 + acol];

        __builtin_amdgcn_s_setprio(1);
#pragma unroll
        for (int mi = 0; mi < 4; mi++)
#pragma unroll
            for (int ni = 0; ni < 4; ni++)
                acc[mi][ni] = __builtin_amdgcn_mfma_f32_16x16x32_bf16(
                    af[mi], bfr[ni], acc[mi][ni], 0, 0, 0);
        __builtin_amdgcn_s_setprio(0);

        if (t + 1 < nt) {
            if (t + 2 < nt) { asm volatile("s_waitcnt vmcnt(4)" ::: "memory"); }
            else            { asm volatile("s_waitcnt vmcnt(0)" ::: "memory"); }
            __builtin_amdgcn_s_barrier();
        }
        cur += 1; if (cur == 3) cur = 0;
    }
#undef PSTAGE

#pragma unroll
    for (int ni = 0; ni < 4; ni++) {
        const int col = n0 + wn * 64 + ni * 16 + lr;
        const float bv = bias[col];
#pragma unroll
        for (int mi = 0; mi < 4; mi++) {
#pragma unroll
            for (int r = 0; r < 4; r++) {
                const int row = m0 + wm * 64 + mi * 16 + lg * 4 + r;
                out[(size_t)row * N + col] = acc[mi][ni][r] + bv;
            }
        }
    }
}

// ---------------------------------------------------------------------------
// routing scores + top-8
// ---------------------------------------------------------------------------
__global__ void scores_topk(const float* __restrict__ qrt, const float* __restrict__ ren,
                            float* __restrict__ sc_out, float* __restrict__ idx_out)
{
    const int row = blockIdx.x * 64 + threadIdx.x;
    if (row >= B_ * T_) return;
    const int b = row / T_;
    float q[RD];
#pragma unroll
    for (int i = 0; i < RD; i++) q[i] = qrt[(size_t)row * RD + i];
    const float* rb = ren + (size_t)b * NCH * RD;
    float s[NCH];
#pragma unroll 4
    for (int n = 0; n < NCH; n++) {
        float acc = 0.f;
#pragma unroll
        for (int i = 0; i < RD; i++) acc += q[i] * rb[n * RD + i];
        s[n] = acc;
        sc_out[(size_t)row * NCH + n] = acc;
    }
    unsigned mask = 0;
    for (int t = 0; t < TOPB; t++) {
        float best = -INFINITY;
        int bi = 0;
#pragma unroll
        for (int n = 0; n < NCH; n++) {
            const bool ok = !((mask >> n) & 1u) && (s[n] > best);
            if (ok) { best = s[n]; bi = n; }
        }
        mask |= (1u << bi);
        idx_out[(size_t)row * TOPB + t] = (float)bi;
    }
}

// ---------------------------------------------------------------------------
// MFMA bf16 flash attention v12: split-K(2) + SINGLE-buffered K/V (16 KB LDS).
// LDS 32->16 KB lifts residency 5 -> 8 blocks/CU (wave cap, VGPR<=64 via
// launch_bounds(256,8)); split-K keeps blocks phase-diverse so the extra
// barrier per tile is covered by co-resident waves. v8 core otherwise.
// ---------------------------------------------------------------------------
#define SW(row, idx) ((idx) ^ (((row) & 7) << 3))

__global__ __launch_bounds__(256, 8) void attn_mfma(
    const unsigned short* __restrict__ qg, const unsigned short* __restrict__ kg,
    const unsigned short* __restrict__ vg,
    unsigned short* __restrict__ Op0, unsigned short* __restrict__ Op1,
    float2* __restrict__ mlbuf)
{
    const int bid  = blockIdx.x;              // 0..2047
    const int xcd  = bid & 7;
    const int h    = xcd + 8 * ((bid >> 3) & 1);
    const int b    = (bid >> 4) & 1;
    const int rest = bid >> 5;                // 0..63
    const int half = rest & 1;
    const int i    = rest >> 1;               // 0..31
    const int qt   = 31 - i;                  // long blocks first

    const int tid  = threadIdx.x;
    const int wave = tid >> 6;
    const int lane = tid & 63;
    const int lg = lane >> 4;
    const int lr = lane & 15;

    const int bh = b * H_ + h;

    const int ntt = qt + 1;
    const int nh0 = (ntt + 1) >> 1;
    const int kts = half ? nh0 : 0;
    const int kte = half ? ntt : nh0;

    float m_run = -INFINITY, l_run = 0.f;

    if (kts >= kte) {
        if (lg == 0 && wave < 4) {
            const int trow = qt * 64 + wave * 16 + lr;
            mlbuf[(size_t)half * (B_ * H_ * T_) + (size_t)bh * T_ + trow] =
                make_float2(-INFINITY, 0.f);
        }
        return;
    }

    __shared__ short Ks[64 * 64];
    __shared__ short Vt[64 * 64];

    const size_t base = ((size_t)bh * T_) * D_;

    bf16x8 qf0, qf1;
    {
        const short* qp = (const short*)qg + base + (size_t)(qt * 64 + wave * 16 + lr) * D_;
        qf0 = *(const bf16x8*)&qp[lg * 8];
        qf1 = *(const bf16x8*)&qp[32 + lg * 8];
    }

    const int srr = tid >> 2;
    const int sc0 = (tid & 3) * 16;
    const int vrp = tid & 31;
    const int vcg = tid >> 5;
    const int kv0   = 2 * vrp;
    const int vslot = ((kv0 >> 5) << 5) + (((kv0 >> 2) & 3) << 3) +
                      (((kv0 >> 4) & 1) << 2) + (kv0 & 3);

    const int kst0 = SW(srr, srr * 64 + sc0);
    const int kst1 = SW(srr, srr * 64 + sc0 + 8);
    const int rsw = (lr & 7) << 3;

    bf16x8 kreg0, kreg1, vreg0, vreg1;

    f32x4 oacc[4];
#pragma unroll
    for (int r = 0; r < 4; r++) oacc[r] = (f32x4){0.f, 0.f, 0.f, 0.f};
    const int qrow_g = qt * 64 + wave * 16 + lr;

#define VPACK()                                                                 \
    {                                                                           \
        const unsigned* v0d = (const unsigned*)&vreg0;                          \
        const unsigned* v1d = (const unsigned*)&vreg1;                          \
        _Pragma("unroll")                                                       \
        for (int jj = 0; jj < 8; jj++) {                                        \
            const unsigned sel = (jj & 1) ? 0x07060302u : 0x05040100u;          \
            const unsigned dw = __builtin_amdgcn_perm(v1d[jj >> 1], v0d[jj >> 1], sel); \
            *(unsigned*)&Vt[SW(jj, (vcg * 8 + jj) * 64 + vslot)] = dw;          \
        }                                                                       \
    }

    const short* kpn = (const short*)kg + base + (size_t)(kts * 64 + srr) * D_ + sc0;
    const short* vpn = (const short*)vg + base + (size_t)(kts * 64 + kv0) * D_ + vcg * 8;

    // prologue: load tile kts, write to the single buffer, prefetch kts+1
    kreg0 = *(const bf16x8*)kpn;
    kreg1 = *(const bf16x8*)(kpn + 8);
    vreg0 = *(const bf16x8*)vpn;
    vreg1 = *(const bf16x8*)(vpn + D_);
    kpn += 4096; vpn += 4096;

    *(bf16x8*)&Ks[kst0] = kreg0;
    *(bf16x8*)&Ks[kst1] = kreg1;
    VPACK()

    if (kts + 1 < kte) {
        kreg0 = *(const bf16x8*)kpn;
        kreg1 = *(const bf16x8*)(kpn + 8);
        vreg0 = *(const bf16x8*)vpn;
        vreg1 = *(const bf16x8*)(vpn + D_);
        kpn += 4096; vpn += 4096;
    }
    __syncthreads();

    for (int kt = kts; kt < kte; ++kt) {
        // QK^T from the single buffer
        f32x4 s[4];
        __builtin_amdgcn_s_setprio(1);
#pragma unroll
        for (int cb = 0; cb < 4; cb++) {
            const int row = cb * 16 + lr;
            bf16x8 kf0 = *(const bf16x8*)&Ks[(row * 64 + lg * 8) ^ rsw];
            bf16x8 kf1 = *(const bf16x8*)&Ks[(row * 64 + 32 + lg * 8) ^ rsw];
            f32x4 acc = (f32x4){0.f, 0.f, 0.f, 0.f};
            acc = __builtin_amdgcn_mfma_f32_16x16x32_bf16(kf0, qf0, acc, 0, 0, 0);
            acc = __builtin_amdgcn_mfma_f32_16x16x32_bf16(kf1, qf1, acc, 0, 0, 0);
            s[cb] = acc;
        }
        __builtin_amdgcn_s_setprio(0);

        if (kt == qt) {
#pragma unroll
            for (int cb = 0; cb < 4; cb++)
#pragma unroll
                for (int r = 0; r < 4; r++)
                    if (kt * 64 + cb * 16 + lg * 4 + r > qrow_g) s[cb][r] = -INFINITY;
        }

        float rm;
        {
            const float t0 = fmaxf(fmaxf(s[0][0], s[0][1]), fmaxf(s[0][2], s[0][3]));
            const float t1 = fmaxf(fmaxf(s[1][0], s[1][1]), fmaxf(s[1][2], s[1][3]));
            const float t2 = fmaxf(fmaxf(s[2][0], s[2][1]), fmaxf(s[2][2], s[2][3]));
            const float t3 = fmaxf(fmaxf(s[3][0], s[3][1]), fmaxf(s[3][2], s[3][3]));
            rm = fmaxf(fmaxf(t0, t1), fmaxf(t2, t3));
        }
        rm = fmaxf(rm, __shfl_xor(rm, 16));
        rm = fmaxf(rm, __shfl_xor(rm, 32));

        if (!__all(rm <= m_run + 8.0f)) {
            const float mnew = fmaxf(m_run, rm);
            const float fsc  = exp2f(m_run - mnew);
            m_run = mnew;
            l_run *= fsc;
            float fr[4];
#pragma unroll
            for (int r = 0; r < 4; r++) fr[r] = __shfl(fsc, lg * 4 + r);
#pragma unroll
            for (int db = 0; db < 4; db++)
#pragma unroll
                for (int r = 0; r < 4; r++) oacc[db][r] *= fr[r];
        }

        float p[4][4];
#pragma unroll
        for (int cb = 0; cb < 4; cb++)
#pragma unroll
            for (int r = 0; r < 4; r++)
                p[cb][r] = exp2f(s[cb][r] - m_run);
        float rs;
        {
            const float t0 = (p[0][0] + p[0][1]) + (p[0][2] + p[0][3]);
            const float t1 = (p[1][0] + p[1][1]) + (p[1][2] + p[1][3]);
            const float t2 = (p[2][0] + p[2][1]) + (p[2][2] + p[2][3]);
            const float t3 = (p[3][0] + p[3][1]) + (p[3][2] + p[3][3]);
            rs = (t0 + t1) + (t2 + t3);
        }
        rs += __shfl_xor(rs, 16);
        rs += __shfl_xor(rs, 32);
        l_run += rs;

        bf16x8 pf0, pf1;
#pragma unroll
        for (int r = 0; r < 4; r++) {
            pf0[r]     = (short)f2b(p[0][r]);
            pf0[4 + r] = (short)f2b(p[1][r]);
            pf1[r]     = (short)f2b(p[2][r]);
            pf1[4 + r] = (short)f2b(p[3][r]);
        }

        __builtin_amdgcn_s_setprio(1);
#pragma unroll
        for (int db = 0; db < 4; db++) {
            const int row = db * 16 + lr;
            bf16x8 vf0 = *(const bf16x8*)&Vt[(row * 64 + lg * 8) ^ rsw];
            bf16x8 vf1 = *(const bf16x8*)&Vt[(row * 64 + 32 + lg * 8) ^ rsw];
            oacc[db] = __builtin_amdgcn_mfma_f32_16x16x32_bf16(pf0, vf0, oacc[db], 0, 0, 0);
            oacc[db] = __builtin_amdgcn_mfma_f32_16x16x32_bf16(pf1, vf1, oacc[db], 0, 0, 0);
        }
        __builtin_amdgcn_s_setprio(0);

        // single-buffer rotation: readers done -> write next tile -> ready
        if (kt + 1 < kte) {
            __syncthreads();                 // all reads of tile kt complete
            *(bf16x8*)&Ks[kst0] = kreg0;
            *(bf16x8*)&Ks[kst1] = kreg1;
            VPACK()
            if (kt + 2 < kte) {
                kreg0 = *(const bf16x8*)kpn;
                kreg1 = *(const bf16x8*)(kpn + 8);
                vreg0 = *(const bf16x8*)vpn;
                vreg1 = *(const bf16x8*)(vpn + D_);
                kpn += 4096; vpn += 4096;
            }
            __syncthreads();                 // tile kt+1 visible
        }
    }
#undef VPACK

    unsigned short* Op = half ? Op1 : Op0;
#pragma unroll
    for (int r = 0; r < 4; r++) {
        const int trow = qt * 64 + wave * 16 + lg * 4 + r;
        unsigned short* op = Op + ((size_t)bh * T_ + trow) * D_;
#pragma unroll
        for (int db = 0; db < 4; db++)
            op[db * 16 + lr] = f2b(oacc[db][r]);
    }
    if (lg == 0) {
        const int trow = qt * 64 + wave * 16 + lr;
        mlbuf[(size_t)half * (B_ * H_ * T_) + (size_t)bh * T_ + trow] =
            make_float2(m_run, l_run);
    }
}

// ---------------------------------------------------------------------------
// combine partials: y = (O0*w0 + O1*w1) / (l0*w0 + l1*w1), w_i = 2^(m_i - m)
// ---------------------------------------------------------------------------
__global__ __launch_bounds__(256) void combine_kernel(
    const unsigned short* __restrict__ Op0, const unsigned short* __restrict__ Op1,
    const float2* __restrict__ mlbuf, unsigned short* __restrict__ y)
{
    const int ro = blockIdx.x * 16 + (threadIdx.x >> 4);   // 0..65535 (bh*T+t)
    const int d0 = (threadIdx.x & 15) * 4;

    const float2 ml0 = mlbuf[ro];
    const float2 ml1 = mlbuf[B_ * H_ * T_ + ro];
    const float m  = fmaxf(ml0.x, ml1.x);
    const float w0 = exp2f(ml0.x - m);
    const float w1 = exp2f(ml1.x - m);
    const float inv = 1.0f / (ml0.y * w0 + ml1.y * w1);

    const size_t off = (size_t)ro * D_ + d0;
    const ushort4 o0 = *(const ushort4*)&Op0[off];
    const ushort4 o1 = *(const ushort4*)&Op1[off];

    ushort4 res;
    res.x = f2b((b2f(o0.x) * w0 + b2f(o1.x) * w1) * inv);
    res.y = f2b((b2f(o0.y) * w0 + b2f(o1.y) * w1) * inv);
    res.z = f2b((b2f(o0.z) * w0 + b2f(o1.z) * w1) * inv);
    res.w = f2b((b2f(o0.w) * w0 + b2f(o1.w) * w1) * inv);

    const int bh = ro >> 11, t = ro & 2047;
    const int b = bh >> 4, h = bh & 15;
    *(ushort4*)&y[((size_t)(b * T_ + t) * C_) + h * D_ + d0] = res;
}

// ---------------------------------------------------------------------------
extern "C" void kernel_launch(void* const* d_in, const int* in_sizes, int n_in,
                              void* d_out, int out_size, void* d_ws, size_t ws_size,
                              hipStream_t stream)
{
    const float* x       = (const float*)d_in[0];
    const float* Wqkv    = (const float*)d_in[1];
    const float* bqkv    = (const float*)d_in[2];
    const float* Wproj   = (const float*)d_in[3];
    const float* bproj   = (const float*)d_in[4];
    const float* Wrouter = (const float*)d_in[5];
    const float* brouter = (const float*)d_in[6];
    const float* Wq_rt   = (const float*)d_in[7];
    const float* bq_rt   = (const float*)d_in[8];

    float* out = (float*)d_out;
    char*  ws  = (char*)d_ws;

    const size_t MT  = (size_t)B_ * T_;
    const size_t QKV = MT * C_;

    unsigned short* xb   = (unsigned short*)ws;
    unsigned short* Wqt  = xb  + QKV;
    unsigned short* Wpt  = Wqt + (size_t)3 * C_ * C_;
    unsigned short* q    = Wpt + (size_t)C_ * C_;
    unsigned short* k    = q + QKV;
    unsigned short* v    = k + QKV;
    unsigned short* yab  = v + QKV;
    float* cm   = (float*)(yab + QKV);
    float* qrt  = cm  + (size_t)B_ * NCH * C_;
    float* ren  = qrt + MT * RD;
    float2* mlbuf = (float2*)(ren + (size_t)B_ * NCH * RD);       // 2*65536 float2
    unsigned short* Op1 = (unsigned short*)(mlbuf + 2 * B_ * H_ * T_);  // 4Mi bf16
    unsigned short* Op0 = xb;   // xb dead after qkv GEMM — reuse as partial O

    float* y_out   = out;
    float* idx_out = out + QKV;
    float* sc_out  = idx_out + MT * TOPB;
    float* emb_out = sc_out + MT * NCH;

    // 1) fused preprocessing (W transposes, qrt, chunkmean+cast)
    prep_fused<<<2304, 256, 0, stream>>>(x, xb, Wqkv, Wqt, Wproj, Wpt,
                                         Wq_rt, bq_rt, qrt, cm);

    // 2) qkv projection
    gemm_qkv_128x256<<<dim3(384), 512, 0, stream>>>(
        xb, Wqt, bqkv, q, k, v, (int)MT, 3 * C_, C_);

    // 3) routing embeds and top-k
    embeds_kernel<<<8, 256, 0, stream>>>(cm, Wrouter, brouter, emb_out, ren);
    scores_topk<<<(int)(MT / 64), 64, 0, stream>>>(qrt, ren, sc_out, idx_out);

    // 4) split-K flash attention (single-buffered, 8 blocks/CU) + combine
    attn_mfma<<<dim3(2048), 256, 0, stream>>>(q, k, v, Op0, Op1, mlbuf);
    combine_kernel<<<dim3(4096), 256, 0, stream>>>(Op0, Op1, mlbuf, yab);

    // 5) output projection
    gemm_proj_128<<<dim3(C_ / 128, MT / 128), 256, 0, stream>>>(
        yab, Wpt, bproj, y_out, (int)MT, C_, C_);
}

// Round 21
// 175.522 us; speedup vs baseline: 1.6677x; 1.6677x over previous
//
#include <hip/hip_runtime.h>
#include <hip/hip_bf16.h>
#include <math.h>

#define B_   2
#define T_   2048
#define C_   1024
#define H_   16
#define D_   64
#define NCH  32
#define RD   32
#define TOPB 8

typedef __attribute__((ext_vector_type(8))) short bf16x8;
typedef __attribute__((ext_vector_type(4))) float f32x4;

static __device__ __forceinline__ unsigned short f2b(float f) {
    return __bfloat16_as_ushort(__float2bfloat16(f));
}
static __device__ __forceinline__ float b2f(unsigned short u) {
    union { unsigned u32; float f; } c; c.u32 = ((unsigned)u) << 16; return c.f;
}

#define SCALE2 0.18033688f   /* 0.125 * 1.44269504 (log2 domain) */

// ---------------------------------------------------------------------------
// prep_fused v2 (2304 blocks):
//   [0,768)       Wqkv [K][3072] -> Wqt bf16 [3072][K]
//   [768,1024)    Wproj -> Wpt
//   [1024,2048)   qrt = l2norm(x @ Wq_rt + b)
//   [2048,2304)   chunk means + x->bf16 cast fused (single pass over x)
// ---------------------------------------------------------------------------
__global__ __launch_bounds__(256) void prep_fused(
    const float* __restrict__ x, unsigned short* __restrict__ xb,
    const float* __restrict__ Wqkv, unsigned short* __restrict__ Wqt,
    const float* __restrict__ Wproj, unsigned short* __restrict__ Wpt,
    const float* __restrict__ Wq_rt, const float* __restrict__ bq_rt,
    float* __restrict__ qrt, float* __restrict__ cm)
{
    __shared__ float smem[64 * 65];
    const int bid = blockIdx.x;
    const int tid = threadIdx.x;

    if (bid < 1024) {                      // ---- weight transpose+cast
        const float* W; unsigned short* Wt; int N, local;
        if (bid < 768) { W = Wqkv;  Wt = Wqt; N = 3072; local = bid; }
        else           { W = Wproj; Wt = Wpt; N = 1024; local = bid - 768; }
        const int nblk = N >> 6;
        const int n0 = (local % nblk) * 64, k0 = (local / nblk) * 64;
        float (*t)[65] = (float(*)[65])smem;
#pragma unroll
        for (int i = 0; i < 4; i++) {
            const int f = tid + i * 256;
            const int r = f >> 4, c4 = (f & 15) * 4;
            float4 v = *(const float4*)&W[(size_t)(k0 + r) * N + n0 + c4];
            t[r][c4 + 0] = v.x; t[r][c4 + 1] = v.y;
            t[r][c4 + 2] = v.z; t[r][c4 + 3] = v.w;
        }
        __syncthreads();
#pragma unroll
        for (int i = 0; i < 2; i++) {
            const int s = tid + i * 256;
            const int rn = s >> 3, ck8 = (s & 7) * 8;
            bf16x8 o;
#pragma unroll
            for (int j = 0; j < 8; j++) o[j] = (short)f2b(t[ck8 + j][rn]);
            *(bf16x8*)&Wt[(size_t)(n0 + rn) * 1024 + k0 + ck8] = o;
        }
    } else if (bid < 2048) {               // ---- qrt projection + l2norm
        float (*part)[4][32] = (float(*)[4][32])smem;
        const int r0 = (bid - 1024) * 4;
        const int g = tid >> 5;
        const int n = tid & 31;
        const float* w  = Wq_rt + (size_t)(g * 128) * RD + n;
        const float* a0 = x + (size_t)(r0 + 0) * C_ + g * 128;
        const float* a1 = x + (size_t)(r0 + 1) * C_ + g * 128;
        const float* a2 = x + (size_t)(r0 + 2) * C_ + g * 128;
        const float* a3 = x + (size_t)(r0 + 3) * C_ + g * 128;
        float acc0 = 0.f, acc1 = 0.f, acc2 = 0.f, acc3 = 0.f;
#pragma unroll 8
        for (int i = 0; i < 128; i += 4) {
            const float w0 = w[(i + 0) * RD];
            const float w1 = w[(i + 1) * RD];
            const float w2 = w[(i + 2) * RD];
            const float w3 = w[(i + 3) * RD];
            float4 x0 = *(const float4*)&a0[i];
            float4 x1 = *(const float4*)&a1[i];
            float4 x2 = *(const float4*)&a2[i];
            float4 x3 = *(const float4*)&a3[i];
            acc0 += x0.x * w0; acc0 += x0.y * w1; acc0 += x0.z * w2; acc0 += x0.w * w3;
            acc1 += x1.x * w0; acc1 += x1.y * w1; acc1 += x1.z * w2; acc1 += x1.w * w3;
            acc2 += x2.x * w0; acc2 += x2.y * w1; acc2 += x2.z * w2; acc2 += x2.w * w3;
            acc3 += x3.x * w0; acc3 += x3.y * w1; acc3 += x3.z * w2; acc3 += x3.w * w3;
        }
        part[g][0][n] = acc0;
        part[g][1][n] = acc1;
        part[g][2][n] = acc2;
        part[g][3][n] = acc3;
        __syncthreads();
        if (g < 4) {
            float s = part[0][g][n];
#pragma unroll
            for (int gg = 1; gg < 8; gg++) s += part[gg][g][n];
            s += bq_rt[n];
            float ss = s * s;
#pragma unroll
            for (int off = 16; off >= 1; off >>= 1) ss += __shfl_xor(ss, off, 32);
            qrt[(size_t)(r0 + g) * RD + n] = s / fmaxf(sqrtf(ss), 1e-12f);
        }
    } else {                               // ---- chunk means + x->bf16 cast
        const int local = bid - 2048;      // 0..255
        const int bc = local & 63;
        const int b = bc >> 5, n = bc & 31;
        const int c = (local >> 6) * 256 + tid;
        const size_t rowbase = ((size_t)b * T_ + n * 64) * C_ + c;
        float s = 0.f;
        for (int i = 0; i < 64; i++) {
            const float v = x[rowbase + (size_t)i * C_];
            s += v;
            xb[rowbase + (size_t)i * C_] = f2b(v);
        }
        cm[(size_t)bc * C_ + c] = s * (1.0f / 64.0f);
    }
}

// ---------------------------------------------------------------------------
// routing embeds + l2norm fused
// ---------------------------------------------------------------------------
__global__ void embeds_kernel(const float* __restrict__ cm, const float* __restrict__ W,
                              const float* __restrict__ bias,
                              float* __restrict__ emb_out, float* __restrict__ ren)
{
    const int row  = blockIdx.x * 8 + (threadIdx.x >> 5);
    const int lane = threadIdx.x & 31;
    if (row >= B_ * NCH) return;
    const float* a = cm + (size_t)row * C_;
    float acc = 0.f;
    for (int k = 0; k < C_; k += 4) {
        float4 a4 = *(const float4*)&a[k];
        acc += a4.x * W[(k + 0) * RD + lane];
        acc += a4.y * W[(k + 1) * RD + lane];
        acc += a4.z * W[(k + 2) * RD + lane];
        acc += a4.w * W[(k + 3) * RD + lane];
    }
    acc += bias[lane];
    emb_out[(size_t)row * RD + lane] = acc;
    float ss = acc * acc;
#pragma unroll
    for (int off = 16; off >= 1; off >>= 1) ss += __shfl_xor(ss, off, 32);
    ren[(size_t)row * RD + lane] = acc / fmaxf(sqrtf(ss), 1e-12f);
}

// ---------------------------------------------------------------------------
// qkv GEMM, 128x256 tile, 8 waves, tri-buffered + counted vmcnt (R14)
// ---------------------------------------------------------------------------
__global__ __launch_bounds__(512, 4) void gemm_qkv_128x256(
    const unsigned short* __restrict__ A, const unsigned short* __restrict__ Bt,
    const float* __restrict__ bias,
    unsigned short* __restrict__ qp, unsigned short* __restrict__ kp,
    unsigned short* __restrict__ vp, int M, int N, int K)
{
    __shared__ unsigned short lds[3][12288];

    const int tid  = threadIdx.x;
    const int wid  = tid >> 6;
    const int lane = tid & 63;
    const int lr = lane & 15, lg = lane >> 4;
    const int wm = wid >> 2;
    const int wn = wid & 3;

    const int bid = blockIdx.x;
    const int swz = (bid & 7) * 48 + (bid >> 3);
    const int m0 = (swz & 31) << 7;
    const int n0 = (swz >> 5) << 8;

    const int srow = tid >> 2;
    const int sswz = (((srow & 3) ^ ((srow >> 2) & 3)) << 4);
    const int skel = (((tid & 3) << 4) ^ sswz) >> 1;
    const unsigned short* gA  = A  + (size_t)(m0 + srow) * K + skel;
    const unsigned short* gB0 = Bt + (size_t)(n0 + srow) * K + skel;
    const unsigned short* gB1 = Bt + (size_t)(n0 + srow + 128) * K + skel;
    const int lb = wid * 512;

#define QSTAGE(sl, kofs)                                                          \
    __builtin_amdgcn_global_load_lds(                                             \
        (const __attribute__((address_space(1))) int*)(gA + (kofs)),              \
        (__attribute__((address_space(3))) int*)&lds[sl][lb], 16, 0, 0);          \
    __builtin_amdgcn_global_load_lds(                                             \
        (const __attribute__((address_space(1))) int*)(gB0 + (kofs)),             \
        (__attribute__((address_space(3))) int*)&lds[sl][4096 + lb], 16, 0, 0);   \
    __builtin_amdgcn_global_load_lds(                                             \
        (const __attribute__((address_space(1))) int*)(gB1 + (kofs)),             \
        (__attribute__((address_space(3))) int*)&lds[sl][8192 + lb], 16, 0, 0);

    const int rswz = (((lr & 3) ^ ((lr >> 2) & 3)) << 4);
    const int acol = (((lg << 4) ^ rswz) >> 1);

    f32x4 acc[4][4];
#pragma unroll
    for (int i = 0; i < 4; i++)
#pragma unroll
        for (int j = 0; j < 4; j++) acc[i][j] = (f32x4){0.f, 0.f, 0.f, 0.f};

    const int nt = K >> 5;

    QSTAGE(0, 0)
    QSTAGE(1, 32)
    asm volatile("s_waitcnt vmcnt(3)" ::: "memory");
    __builtin_amdgcn_s_barrier();

    int cur = 0;
    for (int t = 0; t < nt; ++t) {
        int s2 = cur + 2; if (s2 >= 3) s2 -= 3;
        if (t + 2 < nt) { QSTAGE(s2, (t + 2) << 5) }

        const unsigned short* sA = &lds[cur][0];
        const unsigned short* sB = &lds[cur][4096];

        bf16x8 af[4], bfr[4];
#pragma unroll
        for (int mi = 0; mi < 4; mi++)
            af[mi] = *(const bf16x8*)&sA[(wm * 64 + mi * 16 + lr) * 32 + acol];
#pragma unroll
        for (int ni = 0; ni < 4; ni++)
            bfr[ni] = *(const bf16x8*)&sB[(wn * 64 + ni * 16 + lr) * 32 + acol];

        __builtin_amdgcn_s_setprio(1);
#pragma unroll
        for (int mi = 0; mi < 4; mi++)
#pragma unroll
            for (int ni = 0; ni < 4; ni++)
                acc[mi][ni] = __builtin_amdgcn_mfma_f32_16x16x32_bf16(
                    af[mi], bfr[ni], acc[mi][ni], 0, 0, 0);
        __builtin_amdgcn_s_setprio(0);

        if (t + 1 < nt) {
            if (t + 2 < nt) { asm volatile("s_waitcnt vmcnt(3)" ::: "memory"); }
            else            { asm volatile("s_waitcnt vmcnt(0)" ::: "memory"); }
            __builtin_amdgcn_s_barrier();
        }
        cur += 1; if (cur == 3) cur = 0;
    }
#undef QSTAGE

#pragma unroll
    for (int ni = 0; ni < 4; ni++) {
        const int col = n0 + wn * 64 + ni * 16 + lr;
        const float bv = bias[col];
        const int which = col >> 10;
        const int c  = col & 1023;
        const int hh = c >> 6;
        const int dd = c & 63;
        unsigned short* dst = (which == 0) ? qp : (which == 1) ? kp : vp;
        const float postmul = (which == 0) ? SCALE2 : 1.0f;
#pragma unroll
        for (int mi = 0; mi < 4; mi++) {
#pragma unroll
            for (int r = 0; r < 4; r++) {
                const int row = m0 + wm * 64 + mi * 16 + lg * 4 + r;
                const int bb = row >> 11, tt = row & 2047;
                dst[(((size_t)bb * H_ + hh) * T_ + tt) * D_ + dd] =
                    f2b((acc[mi][ni][r] + bv) * postmul);
            }
        }
    }
}

// ---------------------------------------------------------------------------
// proj GEMM, 128x128 tile, tri-buffered + counted vmcnt + swizzle (R12)
// ---------------------------------------------------------------------------
__global__ __launch_bounds__(256, 1) void gemm_proj_128(
    const unsigned short* __restrict__ A, const unsigned short* __restrict__ Bt,
    const float* __restrict__ bias, float* __restrict__ out, int M, int N, int K)
{
    __shared__ unsigned short lds[3][2][4096];

    const int tid  = threadIdx.x;
    const int lane = tid & 63;
    const int wave = tid >> 6;
    const int lr = lane & 15, lg = lane >> 4;
    const int wm = wave >> 1, wn = wave & 1;
    const int n0 = blockIdx.x * 128, m0 = blockIdx.y * 128;

    const int srow = tid >> 2;
    const int sswz = (((srow & 3) ^ ((srow >> 2) & 3)) << 4);
    const int skel = (((tid & 3) << 4) ^ sswz) >> 1;
    const unsigned short* gA0 = A  + (size_t)(m0 + srow) * K + skel;
    const unsigned short* gA1 = A  + (size_t)(m0 + srow + 64) * K + skel;
    const unsigned short* gB0 = Bt + (size_t)(n0 + srow) * K + skel;
    const unsigned short* gB1 = Bt + (size_t)(n0 + srow + 64) * K + skel;
    const int ldb = (tid & 0xC0) * 8;

#define PSTAGE(sl, kofs)                                                          \
    __builtin_amdgcn_global_load_lds(                                             \
        (const __attribute__((address_space(1))) int*)(gA0 + (kofs)),             \
        (__attribute__((address_space(3))) int*)&lds[sl][0][ldb], 16, 0, 0);      \
    __builtin_amdgcn_global_load_lds(                                             \
        (const __attribute__((address_space(1))) int*)(gA1 + (kofs)),             \
        (__attribute__((address_space(3))) int*)&lds[sl][0][2048 + ldb], 16, 0, 0); \
    __builtin_amdgcn_global_load_lds(                                             \
        (const __attribute__((address_space(1))) int*)(gB0 + (kofs)),             \
        (__attribute__((address_space(3))) int*)&lds[sl][1][ldb], 16, 0, 0);      \
    __builtin_amdgcn_global_load_lds(                                             \
        (const __attribute__((address_space(1))) int*)(gB1 + (kofs)),             \
        (__attribute__((address_space(3))) int*)&lds[sl][1][2048 + ldb], 16, 0, 0);

    const int rswz = (((lr & 3) ^ ((lr >> 2) & 3)) << 4);
    const int acol = (((lg << 4) ^ rswz) >> 1);

    f32x4 acc[4][4];
#pragma unroll
    for (int i = 0; i < 4; i++)
#pragma unroll
        for (int j = 0; j < 4; j++) acc[i][j] = (f32x4){0.f, 0.f, 0.f, 0.f};

    const int nt = K >> 5;

    PSTAGE(0, 0)
    PSTAGE(1, 32)
    asm volatile("s_waitcnt vmcnt(4)" ::: "memory");
    __builtin_amdgcn_s_barrier();

    int cur = 0;
    for (int t = 0; t < nt; ++t) {
        int s2 = cur + 2; if (s2 >= 3) s2 -= 3;
        if (t + 2 < nt) { PSTAGE(s2, (t + 2) << 5) }

        const unsigned short* sA = &lds[cur][0][0];
        const unsigned short* sB = &lds[cur][1][0];

        bf16x8 af[4], bfr[4];
#pragma unroll
        for (int mi = 0; mi < 4; mi++)
            af[mi] = *(const bf16x8*)&sA[(wm * 64 + mi * 16 + lr) * 32 + acol];
#pragma unroll
        for (int ni = 0; ni < 4; ni++)
            bfr[ni] = *(const bf16x8*)&sB[(wn * 64 + ni * 16 + lr) * 32 + acol];

        __builtin_amdgcn_s_setprio(1);
#pragma unroll
        for (int mi = 0; mi < 4; mi++)
#pragma unroll
            for (int ni = 0; ni < 4; ni++)
                acc[mi][ni] = __builtin_amdgcn_mfma_f32_16x16x32_bf16(
                    af[mi], bfr[ni], acc[mi][ni], 0, 0, 0);
        __builtin_amdgcn_s_setprio(0);

        if (t + 1 < nt) {
            if (t + 2 < nt) { asm volatile("s_waitcnt vmcnt(4)" ::: "memory"); }
            else            { asm volatile("s_waitcnt vmcnt(0)" ::: "memory"); }
            __builtin_amdgcn_s_barrier();
        }
        cur += 1; if (cur == 3) cur = 0;
    }
#undef PSTAGE

#pragma unroll
    for (int ni = 0; ni < 4; ni++) {
        const int col = n0 + wn * 64 + ni * 16 + lr;
        const float bv = bias[col];
#pragma unroll
        for (int mi = 0; mi < 4; mi++) {
#pragma unroll
            for (int r = 0; r < 4; r++) {
                const int row = m0 + wm * 64 + mi * 16 + lg * 4 + r;
                out[(size_t)row * N + col] = acc[mi][ni][r] + bv;
            }
        }
    }
}

// ---------------------------------------------------------------------------
// routing scores + top-8
// ---------------------------------------------------------------------------
__global__ void scores_topk(const float* __restrict__ qrt, const float* __restrict__ ren,
                            float* __restrict__ sc_out, float* __restrict__ idx_out)
{
    const int row = blockIdx.x * 64 + threadIdx.x;
    if (row >= B_ * T_) return;
    const int b = row / T_;
    float q[RD];
#pragma unroll
    for (int i = 0; i < RD; i++) q[i] = qrt[(size_t)row * RD + i];
    const float* rb = ren + (size_t)b * NCH * RD;
    float s[NCH];
#pragma unroll 4
    for (int n = 0; n < NCH; n++) {
        float acc = 0.f;
#pragma unroll
        for (int i = 0; i < RD; i++) acc += q[i] * rb[n * RD + i];
        s[n] = acc;
        sc_out[(size_t)row * NCH + n] = acc;
    }
    unsigned mask = 0;
    for (int t = 0; t < TOPB; t++) {
        float best = -INFINITY;
        int bi = 0;
#pragma unroll
        for (int n = 0; n < NCH; n++) {
            const bool ok = !((mask >> n) & 1u) && (s[n] > best);
            if (ok) { best = s[n]; bi = n; }
        }
        mask |= (1u << bi);
        idx_out[(size_t)row * TOPB + t] = (float)bi;
    }
}

// ---------------------------------------------------------------------------
// MFMA bf16 flash attention v10: SPLIT-K (factor 2), v8 core. (R16/R19 proven)
// ---------------------------------------------------------------------------
#define SW(row, idx) ((idx) ^ (((row) & 7) << 3))

__global__ __launch_bounds__(256) void attn_mfma(
    const unsigned short* __restrict__ qg, const unsigned short* __restrict__ kg,
    const unsigned short* __restrict__ vg,
    unsigned short* __restrict__ Op0, unsigned short* __restrict__ Op1,
    float2* __restrict__ mlbuf)
{
    const int bid  = blockIdx.x;              // 0..2047
    const int xcd  = bid & 7;
    const int h    = xcd + 8 * ((bid >> 3) & 1);
    const int b    = (bid >> 4) & 1;
    const int rest = bid >> 5;                // 0..63
    const int half = rest & 1;
    const int i    = rest >> 1;               // 0..31
    const int qt   = 31 - i;                  // long blocks first

    const int tid  = threadIdx.x;
    const int wave = tid >> 6;
    const int lane = tid & 63;
    const int lg = lane >> 4;
    const int lr = lane & 15;

    const int bh = b * H_ + h;

    const int ntt = qt + 1;
    const int nh0 = (ntt + 1) >> 1;
    const int kts = half ? nh0 : 0;
    const int kte = half ? ntt : nh0;

    float m_run = -INFINITY, l_run = 0.f;

    if (kts >= kte) {
        if (lg == 0 && wave < 4) {
            const int trow = qt * 64 + wave * 16 + lr;
            mlbuf[(size_t)half * (B_ * H_ * T_) + (size_t)bh * T_ + trow] =
                make_float2(-INFINITY, 0.f);
        }
        return;
    }

    __shared__ short Ks[2][64 * 64];
    __shared__ short Vt[2][64 * 64];

    const size_t base = ((size_t)bh * T_) * D_;

    bf16x8 qf0, qf1;
    {
        const short* qp = (const short*)qg + base + (size_t)(qt * 64 + wave * 16 + lr) * D_;
        qf0 = *(const bf16x8*)&qp[lg * 8];
        qf1 = *(const bf16x8*)&qp[32 + lg * 8];
    }

    const int srr = tid >> 2;
    const int sc0 = (tid & 3) * 16;
    const int vrp = tid & 31;
    const int vcg = tid >> 5;
    const int kv0   = 2 * vrp;
    const int vslot = ((kv0 >> 5) << 5) + (((kv0 >> 2) & 3) << 3) +
                      (((kv0 >> 4) & 1) << 2) + (kv0 & 3);

    const int kst0 = SW(srr, srr * 64 + sc0);
    const int kst1 = SW(srr, srr * 64 + sc0 + 8);
    const int rsw = (lr & 7) << 3;

    bf16x8 kreg0, kreg1, vreg0, vreg1;

    f32x4 oacc[4];
#pragma unroll
    for (int r = 0; r < 4; r++) oacc[r] = (f32x4){0.f, 0.f, 0.f, 0.f};
    const int qrow_g = qt * 64 + wave * 16 + lr;

#define VPACK(buf)                                                              \
    {                                                                           \
        const unsigned* v0d = (const unsigned*)&vreg0;                          \
        const unsigned* v1d = (const unsigned*)&vreg1;                          \
        _Pragma("unroll")                                                       \
        for (int jj = 0; jj < 8; jj++) {                                        \
            const unsigned sel = (jj & 1) ? 0x07060302u : 0x05040100u;          \
            const unsigned dw = __builtin_amdgcn_perm(v1d[jj >> 1], v0d[jj >> 1], sel); \
            *(unsigned*)&Vt[buf][SW(jj, (vcg * 8 + jj) * 64 + vslot)] = dw;     \
        }                                                                       \
    }

    const short* kpn = (const short*)kg + base + (size_t)(kts * 64 + srr) * D_ + sc0;
    const short* vpn = (const short*)vg + base + (size_t)(kts * 64 + kv0) * D_ + vcg * 8;

    kreg0 = *(const bf16x8*)kpn;
    kreg1 = *(const bf16x8*)(kpn + 8);
    vreg0 = *(const bf16x8*)vpn;
    vreg1 = *(const bf16x8*)(vpn + D_);
    kpn += 4096; vpn += 4096;

    *(bf16x8*)&Ks[0][kst0] = kreg0;
    *(bf16x8*)&Ks[0][kst1] = kreg1;
    VPACK(0)

    if (kts + 1 < kte) {
        kreg0 = *(const bf16x8*)kpn;
        kreg1 = *(const bf16x8*)(kpn + 8);
        vreg0 = *(const bf16x8*)vpn;
        vreg1 = *(const bf16x8*)(vpn + D_);
        kpn += 4096; vpn += 4096;
    }
    __syncthreads();

    for (int kt = kts; kt < kte; ++kt) {
        const int cur = (kt - kts) & 1;

        if (kt + 1 < kte) {
            *(bf16x8*)&Ks[cur ^ 1][kst0] = kreg0;
            *(bf16x8*)&Ks[cur ^ 1][kst1] = kreg1;
            VPACK(cur ^ 1)
        }
        if (kt + 2 < kte) {
            kreg0 = *(const bf16x8*)kpn;
            kreg1 = *(const bf16x8*)(kpn + 8);
            vreg0 = *(const bf16x8*)vpn;
            vreg1 = *(const bf16x8*)(vpn + D_);
            kpn += 4096; vpn += 4096;
        }

        f32x4 s[4];
        __builtin_amdgcn_s_setprio(1);
#pragma unroll
        for (int cb = 0; cb < 4; cb++) {
            const int row = cb * 16 + lr;
            bf16x8 kf0 = *(const bf16x8*)&Ks[cur][(row * 64 + lg * 8) ^ rsw];
            bf16x8 kf1 = *(const bf16x8*)&Ks[cur][(row * 64 + 32 + lg * 8) ^ rsw];
            f32x4 acc = (f32x4){0.f, 0.f, 0.f, 0.f};
            acc = __builtin_amdgcn_mfma_f32_16x16x32_bf16(kf0, qf0, acc, 0, 0, 0);
            acc = __builtin_amdgcn_mfma_f32_16x16x32_bf16(kf1, qf1, acc, 0, 0, 0);
            s[cb] = acc;
        }
        __builtin_amdgcn_s_setprio(0);

        if (kt == qt) {
#pragma unroll
            for (int cb = 0; cb < 4; cb++)
#pragma unroll
                for (int r = 0; r < 4; r++)
                    if (kt * 64 + cb * 16 + lg * 4 + r > qrow_g) s[cb][r] = -INFINITY;
        }

        float rm;
        {
            const float t0 = fmaxf(fmaxf(s[0][0], s[0][1]), fmaxf(s[0][2], s[0][3]));
            const float t1 = fmaxf(fmaxf(s[1][0], s[1][1]), fmaxf(s[1][2], s[1][3]));
            const float t2 = fmaxf(fmaxf(s[2][0], s[2][1]), fmaxf(s[2][2], s[2][3]));
            const float t3 = fmaxf(fmaxf(s[3][0], s[3][1]), fmaxf(s[3][2], s[3][3]));
            rm = fmaxf(fmaxf(t0, t1), fmaxf(t2, t3));
        }
        rm = fmaxf(rm, __shfl_xor(rm, 16));
        rm = fmaxf(rm, __shfl_xor(rm, 32));

        if (!__all(rm <= m_run + 8.0f)) {
            const float mnew = fmaxf(m_run, rm);
            const float fsc  = exp2f(m_run - mnew);
            m_run = mnew;
            l_run *= fsc;
            float fr[4];
#pragma unroll
            for (int r = 0; r < 4; r++) fr[r] = __shfl(fsc, lg * 4 + r);
#pragma unroll
            for (int db = 0; db < 4; db++)
#pragma unroll
                for (int r = 0; r < 4; r++) oacc[db][r] *= fr[r];
        }

        float p[4][4];
#pragma unroll
        for (int cb = 0; cb < 4; cb++)
#pragma unroll
            for (int r = 0; r < 4; r++)
                p[cb][r] = exp2f(s[cb][r] - m_run);
        float rs;
        {
            const float t0 = (p[0][0] + p[0][1]) + (p[0][2] + p[0][3]);
            const float t1 = (p[1][0] + p[1][1]) + (p[1][2] + p[1][3]);
            const float t2 = (p[2][0] + p[2][1]) + (p[2][2] + p[2][3]);
            const float t3 = (p[3][0] + p[3][1]) + (p[3][2] + p[3][3]);
            rs = (t0 + t1) + (t2 + t3);
        }
        rs += __shfl_xor(rs, 16);
        rs += __shfl_xor(rs, 32);
        l_run += rs;

        bf16x8 pf0, pf1;
#pragma unroll
        for (int r = 0; r < 4; r++) {
            pf0[r]     = (short)f2b(p[0][r]);
            pf0[4 + r] = (short)f2b(p[1][r]);
            pf1[r]     = (short)f2b(p[2][r]);
            pf1[4 + r] = (short)f2b(p[3][r]);
        }

        __builtin_amdgcn_s_setprio(1);
#pragma unroll
        for (int db = 0; db < 4; db++) {
            const int row = db * 16 + lr;
            bf16x8 vf0 = *(const bf16x8*)&Vt[cur][(row * 64 + lg * 8) ^ rsw];
            bf16x8 vf1 = *(const bf16x8*)&Vt[cur][(row * 64 + 32 + lg * 8) ^ rsw];
            oacc[db] = __builtin_amdgcn_mfma_f32_16x16x32_bf16(pf0, vf0, oacc[db], 0, 0, 0);
            oacc[db] = __builtin_amdgcn_mfma_f32_16x16x32_bf16(pf1, vf1, oacc[db], 0, 0, 0);
        }
        __builtin_amdgcn_s_setprio(0);

        __syncthreads();
    }
#undef VPACK

    unsigned short* Op = half ? Op1 : Op0;
#pragma unroll
    for (int r = 0; r < 4; r++) {
        const int trow = qt * 64 + wave * 16 + lg * 4 + r;
        unsigned short* op = Op + ((size_t)bh * T_ + trow) * D_;
#pragma unroll
        for (int db = 0; db < 4; db++)
            op[db * 16 + lr] = f2b(oacc[db][r]);
    }
    if (lg == 0) {
        const int trow = qt * 64 + wave * 16 + lr;
        mlbuf[(size_t)half * (B_ * H_ * T_) + (size_t)bh * T_ + trow] =
            make_float2(m_run, l_run);
    }
}

// ---------------------------------------------------------------------------
// combine partials: y = (O0*w0 + O1*w1) / (l0*w0 + l1*w1), w_i = 2^(m_i - m)
// ---------------------------------------------------------------------------
__global__ __launch_bounds__(256) void combine_kernel(
    const unsigned short* __restrict__ Op0, const unsigned short* __restrict__ Op1,
    const float2* __restrict__ mlbuf, unsigned short* __restrict__ y)
{
    const int ro = blockIdx.x * 16 + (threadIdx.x >> 4);   // 0..65535 (bh*T+t)
    const int d0 = (threadIdx.x & 15) * 4;

    const float2 ml0 = mlbuf[ro];
    const float2 ml1 = mlbuf[B_ * H_ * T_ + ro];
    const float m  = fmaxf(ml0.x, ml1.x);
    const float w0 = exp2f(ml0.x - m);
    const float w1 = exp2f(ml1.x - m);
    const float inv = 1.0f / (ml0.y * w0 + ml1.y * w1);

    const size_t off = (size_t)ro * D_ + d0;
    const ushort4 o0 = *(const ushort4*)&Op0[off];
    const ushort4 o1 = *(const ushort4*)&Op1[off];

    ushort4 res;
    res.x = f2b((b2f(o0.x) * w0 + b2f(o1.x) * w1) * inv);
    res.y = f2b((b2f(o0.y) * w0 + b2f(o1.y) * w1) * inv);
    res.z = f2b((b2f(o0.z) * w0 + b2f(o1.z) * w1) * inv);
    res.w = f2b((b2f(o0.w) * w0 + b2f(o1.w) * w1) * inv);

    const int bh = ro >> 11, t = ro & 2047;
    const int b = bh >> 4, h = bh & 15;
    *(ushort4*)&y[((size_t)(b * T_ + t) * C_) + h * D_ + d0] = res;
}

// ---------------------------------------------------------------------------
extern "C" void kernel_launch(void* const* d_in, const int* in_sizes, int n_in,
                              void* d_out, int out_size, void* d_ws, size_t ws_size,
                              hipStream_t stream)
{
    const float* x       = (const float*)d_in[0];
    const float* Wqkv    = (const float*)d_in[1];
    const float* bqkv    = (const float*)d_in[2];
    const float* Wproj   = (const float*)d_in[3];
    const float* bproj   = (const float*)d_in[4];
    const float* Wrouter = (const float*)d_in[5];
    const float* brouter = (const float*)d_in[6];
    const float* Wq_rt   = (const float*)d_in[7];
    const float* bq_rt   = (const float*)d_in[8];

    float* out = (float*)d_out;
    char*  ws  = (char*)d_ws;

    const size_t MT  = (size_t)B_ * T_;
    const size_t QKV = MT * C_;

    unsigned short* xb   = (unsigned short*)ws;
    unsigned short* Wqt  = xb  + QKV;
    unsigned short* Wpt  = Wqt + (size_t)3 * C_ * C_;
    unsigned short* q    = Wpt + (size_t)C_ * C_;
    unsigned short* k    = q + QKV;
    unsigned short* v    = k + QKV;
    unsigned short* yab  = v + QKV;
    float* cm   = (float*)(yab + QKV);
    float* qrt  = cm  + (size_t)B_ * NCH * C_;
    float* ren  = qrt + MT * RD;
    float2* mlbuf = (float2*)(ren + (size_t)B_ * NCH * RD);       // 2*65536 float2
    unsigned short* Op1 = (unsigned short*)(mlbuf + 2 * B_ * H_ * T_);  // 4Mi bf16
    unsigned short* Op0 = xb;   // xb dead after qkv GEMM — reuse as partial O

    float* y_out   = out;
    float* idx_out = out + QKV;
    float* sc_out  = idx_out + MT * TOPB;
    float* emb_out = sc_out + MT * NCH;

    // 1) fused preprocessing (W transposes, qrt, chunkmean+cast)
    prep_fused<<<2304, 256, 0, stream>>>(x, xb, Wqkv, Wqt, Wproj, Wpt,
                                         Wq_rt, bq_rt, qrt, cm);

    // 2) qkv projection
    gemm_qkv_128x256<<<dim3(384), 512, 0, stream>>>(
        xb, Wqt, bqkv, q, k, v, (int)MT, 3 * C_, C_);

    // 3) routing embeds and top-k
    embeds_kernel<<<8, 256, 0, stream>>>(cm, Wrouter, brouter, emb_out, ren);
    scores_topk<<<(int)(MT / 64), 64, 0, stream>>>(qrt, ren, sc_out, idx_out);

    // 4) split-K flash attention (partials) + combine -> bf16 yab
    attn_mfma<<<dim3(2048), 256, 0, stream>>>(q, k, v, Op0, Op1, mlbuf);
    combine_kernel<<<dim3(4096), 256, 0, stream>>>(Op0, Op1, mlbuf, yab);

    // 5) output projection
    gemm_proj_128<<<dim3(C_ / 128, MT / 128), 256, 0, stream>>>(
        yab, Wpt, bproj, y_out, (int)MT, C_, C_);
}

// Round 22
// 174.774 us; speedup vs baseline: 1.6748x; 1.0043x over previous
//
#include <hip/hip_runtime.h>
#include <hip/hip_bf16.h>
#include <math.h>

#define B_   2
#define T_   2048
#define C_   1024
#define H_   16
#define D_   64
#define NCH  32
#define RD   32
#define TOPB 8

typedef __attribute__((ext_vector_type(8))) short bf16x8;
typedef __attribute__((ext_vector_type(4))) float f32x4;

static __device__ __forceinline__ unsigned short f2b(float f) {
    return __bfloat16_as_ushort(__float2bfloat16(f));
}
static __device__ __forceinline__ float b2f(unsigned short u) {
    union { unsigned u32; float f; } c; c.u32 = ((unsigned)u) << 16; return c.f;
}

#define SCALE2 0.18033688f   /* 0.125 * 1.44269504 (log2 domain) */

// ---------------------------------------------------------------------------
// prep_fused v2 (2304 blocks): W transposes, qrt+l2norm, chunkmean+cast
// ---------------------------------------------------------------------------
__global__ __launch_bounds__(256) void prep_fused(
    const float* __restrict__ x, unsigned short* __restrict__ xb,
    const float* __restrict__ Wqkv, unsigned short* __restrict__ Wqt,
    const float* __restrict__ Wproj, unsigned short* __restrict__ Wpt,
    const float* __restrict__ Wq_rt, const float* __restrict__ bq_rt,
    float* __restrict__ qrt, float* __restrict__ cm)
{
    __shared__ float smem[64 * 65];
    const int bid = blockIdx.x;
    const int tid = threadIdx.x;

    if (bid < 1024) {                      // ---- weight transpose+cast
        const float* W; unsigned short* Wt; int N, local;
        if (bid < 768) { W = Wqkv;  Wt = Wqt; N = 3072; local = bid; }
        else           { W = Wproj; Wt = Wpt; N = 1024; local = bid - 768; }
        const int nblk = N >> 6;
        const int n0 = (local % nblk) * 64, k0 = (local / nblk) * 64;
        float (*t)[65] = (float(*)[65])smem;
#pragma unroll
        for (int i = 0; i < 4; i++) {
            const int f = tid + i * 256;
            const int r = f >> 4, c4 = (f & 15) * 4;
            float4 v = *(const float4*)&W[(size_t)(k0 + r) * N + n0 + c4];
            t[r][c4 + 0] = v.x; t[r][c4 + 1] = v.y;
            t[r][c4 + 2] = v.z; t[r][c4 + 3] = v.w;
        }
        __syncthreads();
#pragma unroll
        for (int i = 0; i < 2; i++) {
            const int s = tid + i * 256;
            const int rn = s >> 3, ck8 = (s & 7) * 8;
            bf16x8 o;
#pragma unroll
            for (int j = 0; j < 8; j++) o[j] = (short)f2b(t[ck8 + j][rn]);
            *(bf16x8*)&Wt[(size_t)(n0 + rn) * 1024 + k0 + ck8] = o;
        }
    } else if (bid < 2048) {               // ---- qrt projection + l2norm
        float (*part)[4][32] = (float(*)[4][32])smem;
        const int r0 = (bid - 1024) * 4;
        const int g = tid >> 5;
        const int n = tid & 31;
        const float* w  = Wq_rt + (size_t)(g * 128) * RD + n;
        const float* a0 = x + (size_t)(r0 + 0) * C_ + g * 128;
        const float* a1 = x + (size_t)(r0 + 1) * C_ + g * 128;
        const float* a2 = x + (size_t)(r0 + 2) * C_ + g * 128;
        const float* a3 = x + (size_t)(r0 + 3) * C_ + g * 128;
        float acc0 = 0.f, acc1 = 0.f, acc2 = 0.f, acc3 = 0.f;
#pragma unroll 8
        for (int i = 0; i < 128; i += 4) {
            const float w0 = w[(i + 0) * RD];
            const float w1 = w[(i + 1) * RD];
            const float w2 = w[(i + 2) * RD];
            const float w3 = w[(i + 3) * RD];
            float4 x0 = *(const float4*)&a0[i];
            float4 x1 = *(const float4*)&a1[i];
            float4 x2 = *(const float4*)&a2[i];
            float4 x3 = *(const float4*)&a3[i];
            acc0 += x0.x * w0; acc0 += x0.y * w1; acc0 += x0.z * w2; acc0 += x0.w * w3;
            acc1 += x1.x * w0; acc1 += x1.y * w1; acc1 += x1.z * w2; acc1 += x1.w * w3;
            acc2 += x2.x * w0; acc2 += x2.y * w1; acc2 += x2.z * w2; acc2 += x2.w * w3;
            acc3 += x3.x * w0; acc3 += x3.y * w1; acc3 += x3.z * w2; acc3 += x3.w * w3;
        }
        part[g][0][n] = acc0;
        part[g][1][n] = acc1;
        part[g][2][n] = acc2;
        part[g][3][n] = acc3;
        __syncthreads();
        if (g < 4) {
            float s = part[0][g][n];
#pragma unroll
            for (int gg = 1; gg < 8; gg++) s += part[gg][g][n];
            s += bq_rt[n];
            float ss = s * s;
#pragma unroll
            for (int off = 16; off >= 1; off >>= 1) ss += __shfl_xor(ss, off, 32);
            qrt[(size_t)(r0 + g) * RD + n] = s / fmaxf(sqrtf(ss), 1e-12f);
        }
    } else {                               // ---- chunk means + x->bf16 cast
        const int local = bid - 2048;      // 0..255
        const int bc = local & 63;
        const int b = bc >> 5, n = bc & 31;
        const int c = (local >> 6) * 256 + tid;
        const size_t rowbase = ((size_t)b * T_ + n * 64) * C_ + c;
        float s = 0.f;
        for (int i = 0; i < 64; i++) {
            const float v = x[rowbase + (size_t)i * C_];
            s += v;
            xb[rowbase + (size_t)i * C_] = f2b(v);
        }
        cm[(size_t)bc * C_ + c] = s * (1.0f / 64.0f);
    }
}

// ---------------------------------------------------------------------------
// routing embeds + l2norm fused
// ---------------------------------------------------------------------------
__global__ void embeds_kernel(const float* __restrict__ cm, const float* __restrict__ W,
                              const float* __restrict__ bias,
                              float* __restrict__ emb_out, float* __restrict__ ren)
{
    const int row  = blockIdx.x * 8 + (threadIdx.x >> 5);
    const int lane = threadIdx.x & 31;
    if (row >= B_ * NCH) return;
    const float* a = cm + (size_t)row * C_;
    float acc = 0.f;
    for (int k = 0; k < C_; k += 4) {
        float4 a4 = *(const float4*)&a[k];
        acc += a4.x * W[(k + 0) * RD + lane];
        acc += a4.y * W[(k + 1) * RD + lane];
        acc += a4.z * W[(k + 2) * RD + lane];
        acc += a4.w * W[(k + 3) * RD + lane];
    }
    acc += bias[lane];
    emb_out[(size_t)row * RD + lane] = acc;
    float ss = acc * acc;
#pragma unroll
    for (int off = 16; off >= 1; off >>= 1) ss += __shfl_xor(ss, off, 32);
    ren[(size_t)row * RD + lane] = acc / fmaxf(sqrtf(ss), 1e-12f);
}

// ---------------------------------------------------------------------------
// qkv GEMM, 128x256 tile, 8 waves, tri-buffered + counted vmcnt (R14)
// ---------------------------------------------------------------------------
__global__ __launch_bounds__(512, 4) void gemm_qkv_128x256(
    const unsigned short* __restrict__ A, const unsigned short* __restrict__ Bt,
    const float* __restrict__ bias,
    unsigned short* __restrict__ qp, unsigned short* __restrict__ kp,
    unsigned short* __restrict__ vp, int M, int N, int K)
{
    __shared__ unsigned short lds[3][12288];

    const int tid  = threadIdx.x;
    const int wid  = tid >> 6;
    const int lane = tid & 63;
    const int lr = lane & 15, lg = lane >> 4;
    const int wm = wid >> 2;
    const int wn = wid & 3;

    const int bid = blockIdx.x;
    const int swz = (bid & 7) * 48 + (bid >> 3);
    const int m0 = (swz & 31) << 7;
    const int n0 = (swz >> 5) << 8;

    const int srow = tid >> 2;
    const int sswz = (((srow & 3) ^ ((srow >> 2) & 3)) << 4);
    const int skel = (((tid & 3) << 4) ^ sswz) >> 1;
    const unsigned short* gA  = A  + (size_t)(m0 + srow) * K + skel;
    const unsigned short* gB0 = Bt + (size_t)(n0 + srow) * K + skel;
    const unsigned short* gB1 = Bt + (size_t)(n0 + srow + 128) * K + skel;
    const int lb = wid * 512;

#define QSTAGE(sl, kofs)                                                          \
    __builtin_amdgcn_global_load_lds(                                             \
        (const __attribute__((address_space(1))) int*)(gA + (kofs)),              \
        (__attribute__((address_space(3))) int*)&lds[sl][lb], 16, 0, 0);          \
    __builtin_amdgcn_global_load_lds(                                             \
        (const __attribute__((address_space(1))) int*)(gB0 + (kofs)),             \
        (__attribute__((address_space(3))) int*)&lds[sl][4096 + lb], 16, 0, 0);   \
    __builtin_amdgcn_global_load_lds(                                             \
        (const __attribute__((address_space(1))) int*)(gB1 + (kofs)),             \
        (__attribute__((address_space(3))) int*)&lds[sl][8192 + lb], 16, 0, 0);

    const int rswz = (((lr & 3) ^ ((lr >> 2) & 3)) << 4);
    const int acol = (((lg << 4) ^ rswz) >> 1);

    f32x4 acc[4][4];
#pragma unroll
    for (int i = 0; i < 4; i++)
#pragma unroll
        for (int j = 0; j < 4; j++) acc[i][j] = (f32x4){0.f, 0.f, 0.f, 0.f};

    const int nt = K >> 5;

    QSTAGE(0, 0)
    QSTAGE(1, 32)
    asm volatile("s_waitcnt vmcnt(3)" ::: "memory");
    __builtin_amdgcn_s_barrier();

    int cur = 0;
    for (int t = 0; t < nt; ++t) {
        int s2 = cur + 2; if (s2 >= 3) s2 -= 3;
        if (t + 2 < nt) { QSTAGE(s2, (t + 2) << 5) }

        const unsigned short* sA = &lds[cur][0];
        const unsigned short* sB = &lds[cur][4096];

        bf16x8 af[4], bfr[4];
#pragma unroll
        for (int mi = 0; mi < 4; mi++)
            af[mi] = *(const bf16x8*)&sA[(wm * 64 + mi * 16 + lr) * 32 + acol];
#pragma unroll
        for (int ni = 0; ni < 4; ni++)
            bfr[ni] = *(const bf16x8*)&sB[(wn * 64 + ni * 16 + lr) * 32 + acol];

        __builtin_amdgcn_s_setprio(1);
#pragma unroll
        for (int mi = 0; mi < 4; mi++)
#pragma unroll
            for (int ni = 0; ni < 4; ni++)
                acc[mi][ni] = __builtin_amdgcn_mfma_f32_16x16x32_bf16(
                    af[mi], bfr[ni], acc[mi][ni], 0, 0, 0);
        __builtin_amdgcn_s_setprio(0);

        if (t + 1 < nt) {
            if (t + 2 < nt) { asm volatile("s_waitcnt vmcnt(3)" ::: "memory"); }
            else            { asm volatile("s_waitcnt vmcnt(0)" ::: "memory"); }
            __builtin_amdgcn_s_barrier();
        }
        cur += 1; if (cur == 3) cur = 0;
    }
#undef QSTAGE

#pragma unroll
    for (int ni = 0; ni < 4; ni++) {
        const int col = n0 + wn * 64 + ni * 16 + lr;
        const float bv = bias[col];
        const int which = col >> 10;
        const int c  = col & 1023;
        const int hh = c >> 6;
        const int dd = c & 63;
        unsigned short* dst = (which == 0) ? qp : (which == 1) ? kp : vp;
        const float postmul = (which == 0) ? SCALE2 : 1.0f;
#pragma unroll
        for (int mi = 0; mi < 4; mi++) {
#pragma unroll
            for (int r = 0; r < 4; r++) {
                const int row = m0 + wm * 64 + mi * 16 + lg * 4 + r;
                const int bb = row >> 11, tt = row & 2047;
                dst[(((size_t)bb * H_ + hh) * T_ + tt) * D_ + dd] =
                    f2b((acc[mi][ni][r] + bv) * postmul);
            }
        }
    }
}

// ---------------------------------------------------------------------------
// proj GEMM v2: 128x128 tile, 512 threads = 8 waves (2m x 4n, 64x32/wave),
// tri-buffered + counted vmcnt. 2 gload_lds per K-tile -> vmcnt(2) boundaries.
// Doubles wave residency vs the 4-wave version (grid 256 = 1 block/CU).
// ---------------------------------------------------------------------------
__global__ __launch_bounds__(512, 1) void gemm_proj_128(
    const unsigned short* __restrict__ A, const unsigned short* __restrict__ Bt,
    const float* __restrict__ bias, float* __restrict__ out, int M, int N, int K)
{
    __shared__ unsigned short lds[3][2][4096];

    const int tid  = threadIdx.x;
    const int wid  = tid >> 6;
    const int lane = tid & 63;
    const int lr = lane & 15, lg = lane >> 4;
    const int wm = wid >> 2;      // 0..1 (64-row slice)
    const int wn = wid & 3;       // 0..3 (32-col slice)
    const int n0 = blockIdx.x * 128, m0 = blockIdx.y * 128;

    const int srow = tid >> 2;                                   // 0..127
    const int sswz = (((srow & 3) ^ ((srow >> 2) & 3)) << 4);
    const int skel = (((tid & 3) << 4) ^ sswz) >> 1;
    const unsigned short* gA = A  + (size_t)(m0 + srow) * K + skel;
    const unsigned short* gB = Bt + (size_t)(n0 + srow) * K + skel;
    const int lb = wid * 512;     // wave-uniform base (elements)

#define PSTAGE(sl, kofs)                                                          \
    __builtin_amdgcn_global_load_lds(                                             \
        (const __attribute__((address_space(1))) int*)(gA + (kofs)),              \
        (__attribute__((address_space(3))) int*)&lds[sl][0][lb], 16, 0, 0);       \
    __builtin_amdgcn_global_load_lds(                                             \
        (const __attribute__((address_space(1))) int*)(gB + (kofs)),              \
        (__attribute__((address_space(3))) int*)&lds[sl][1][lb], 16, 0, 0);

    const int rswz = (((lr & 3) ^ ((lr >> 2) & 3)) << 4);
    const int acol = (((lg << 4) ^ rswz) >> 1);

    f32x4 acc[4][2];
#pragma unroll
    for (int i = 0; i < 4; i++)
#pragma unroll
        for (int j = 0; j < 2; j++) acc[i][j] = (f32x4){0.f, 0.f, 0.f, 0.f};

    const int nt = K >> 5;

    PSTAGE(0, 0)
    PSTAGE(1, 32)
    asm volatile("s_waitcnt vmcnt(2)" ::: "memory");
    __builtin_amdgcn_s_barrier();

    int cur = 0;
    for (int t = 0; t < nt; ++t) {
        int s2 = cur + 2; if (s2 >= 3) s2 -= 3;
        if (t + 2 < nt) { PSTAGE(s2, (t + 2) << 5) }

        const unsigned short* sA = &lds[cur][0][0];
        const unsigned short* sB = &lds[cur][1][0];

        bf16x8 af[4], bfr[2];
#pragma unroll
        for (int mi = 0; mi < 4; mi++)
            af[mi] = *(const bf16x8*)&sA[(wm * 64 + mi * 16 + lr) * 32 + acol];
#pragma unroll
        for (int ni = 0; ni < 2; ni++)
            bfr[ni] = *(const bf16x8*)&sB[(wn * 32 + ni * 16 + lr) * 32 + acol];

        __builtin_amdgcn_s_setprio(1);
#pragma unroll
        for (int mi = 0; mi < 4; mi++)
#pragma unroll
            for (int ni = 0; ni < 2; ni++)
                acc[mi][ni] = __builtin_amdgcn_mfma_f32_16x16x32_bf16(
                    af[mi], bfr[ni], acc[mi][ni], 0, 0, 0);
        __builtin_amdgcn_s_setprio(0);

        if (t + 1 < nt) {
            if (t + 2 < nt) { asm volatile("s_waitcnt vmcnt(2)" ::: "memory"); }
            else            { asm volatile("s_waitcnt vmcnt(0)" ::: "memory"); }
            __builtin_amdgcn_s_barrier();
        }
        cur += 1; if (cur == 3) cur = 0;
    }
#undef PSTAGE

#pragma unroll
    for (int ni = 0; ni < 2; ni++) {
        const int col = n0 + wn * 32 + ni * 16 + lr;
        const float bv = bias[col];
#pragma unroll
        for (int mi = 0; mi < 4; mi++) {
#pragma unroll
            for (int r = 0; r < 4; r++) {
                const int row = m0 + wm * 64 + mi * 16 + lg * 4 + r;
                out[(size_t)row * N + col] = acc[mi][ni][r] + bv;
            }
        }
    }
}

// ---------------------------------------------------------------------------
// routing scores + top-8
// ---------------------------------------------------------------------------
__global__ void scores_topk(const float* __restrict__ qrt, const float* __restrict__ ren,
                            float* __restrict__ sc_out, float* __restrict__ idx_out)
{
    const int row = blockIdx.x * 64 + threadIdx.x;
    if (row >= B_ * T_) return;
    const int b = row / T_;
    float q[RD];
#pragma unroll
    for (int i = 0; i < RD; i++) q[i] = qrt[(size_t)row * RD + i];
    const float* rb = ren + (size_t)b * NCH * RD;
    float s[NCH];
#pragma unroll 4
    for (int n = 0; n < NCH; n++) {
        float acc = 0.f;
#pragma unroll
        for (int i = 0; i < RD; i++) acc += q[i] * rb[n * RD + i];
        s[n] = acc;
        sc_out[(size_t)row * NCH + n] = acc;
    }
    unsigned mask = 0;
    for (int t = 0; t < TOPB; t++) {
        float best = -INFINITY;
        int bi = 0;
#pragma unroll
        for (int n = 0; n < NCH; n++) {
            const bool ok = !((mask >> n) & 1u) && (s[n] > best);
            if (ok) { best = s[n]; bi = n; }
        }
        mask |= (1u << bi);
        idx_out[(size_t)row * TOPB + t] = (float)bi;
    }
}

// ---------------------------------------------------------------------------
// MFMA bf16 flash attention v10: SPLIT-K (factor 2), v8 core. (R16/R19 proven)
// ---------------------------------------------------------------------------
#define SW(row, idx) ((idx) ^ (((row) & 7) << 3))

__global__ __launch_bounds__(256) void attn_mfma(
    const unsigned short* __restrict__ qg, const unsigned short* __restrict__ kg,
    const unsigned short* __restrict__ vg,
    unsigned short* __restrict__ Op0, unsigned short* __restrict__ Op1,
    float2* __restrict__ mlbuf)
{
    const int bid  = blockIdx.x;              // 0..2047
    const int xcd  = bid & 7;
    const int h    = xcd + 8 * ((bid >> 3) & 1);
    const int b    = (bid >> 4) & 1;
    const int rest = bid >> 5;                // 0..63
    const int half = rest & 1;
    const int i    = rest >> 1;               // 0..31
    const int qt   = 31 - i;                  // long blocks first

    const int tid  = threadIdx.x;
    const int wave = tid >> 6;
    const int lane = tid & 63;
    const int lg = lane >> 4;
    const int lr = lane & 15;

    const int bh = b * H_ + h;

    const int ntt = qt + 1;
    const int nh0 = (ntt + 1) >> 1;
    const int kts = half ? nh0 : 0;
    const int kte = half ? ntt : nh0;

    float m_run = -INFINITY, l_run = 0.f;

    if (kts >= kte) {
        if (lg == 0 && wave < 4) {
            const int trow = qt * 64 + wave * 16 + lr;
            mlbuf[(size_t)half * (B_ * H_ * T_) + (size_t)bh * T_ + trow] =
                make_float2(-INFINITY, 0.f);
        }
        return;
    }

    __shared__ short Ks[2][64 * 64];
    __shared__ short Vt[2][64 * 64];

    const size_t base = ((size_t)bh * T_) * D_;

    bf16x8 qf0, qf1;
    {
        const short* qp = (const short*)qg + base + (size_t)(qt * 64 + wave * 16 + lr) * D_;
        qf0 = *(const bf16x8*)&qp[lg * 8];
        qf1 = *(const bf16x8*)&qp[32 + lg * 8];
    }

    const int srr = tid >> 2;
    const int sc0 = (tid & 3) * 16;
    const int vrp = tid & 31;
    const int vcg = tid >> 5;
    const int kv0   = 2 * vrp;
    const int vslot = ((kv0 >> 5) << 5) + (((kv0 >> 2) & 3) << 3) +
                      (((kv0 >> 4) & 1) << 2) + (kv0 & 3);

    const int kst0 = SW(srr, srr * 64 + sc0);
    const int kst1 = SW(srr, srr * 64 + sc0 + 8);
    const int rsw = (lr & 7) << 3;

    bf16x8 kreg0, kreg1, vreg0, vreg1;

    f32x4 oacc[4];
#pragma unroll
    for (int r = 0; r < 4; r++) oacc[r] = (f32x4){0.f, 0.f, 0.f, 0.f};
    const int qrow_g = qt * 64 + wave * 16 + lr;

#define VPACK(buf)                                                              \
    {                                                                           \
        const unsigned* v0d = (const unsigned*)&vreg0;                          \
        const unsigned* v1d = (const unsigned*)&vreg1;                          \
        _Pragma("unroll")                                                       \
        for (int jj = 0; jj < 8; jj++) {                                        \
            const unsigned sel = (jj & 1) ? 0x07060302u : 0x05040100u;          \
            const unsigned dw = __builtin_amdgcn_perm(v1d[jj >> 1], v0d[jj >> 1], sel); \
            *(unsigned*)&Vt[buf][SW(jj, (vcg * 8 + jj) * 64 + vslot)] = dw;     \
        }                                                                       \
    }

    const short* kpn = (const short*)kg + base + (size_t)(kts * 64 + srr) * D_ + sc0;
    const short* vpn = (const short*)vg + base + (size_t)(kts * 64 + kv0) * D_ + vcg * 8;

    kreg0 = *(const bf16x8*)kpn;
    kreg1 = *(const bf16x8*)(kpn + 8);
    vreg0 = *(const bf16x8*)vpn;
    vreg1 = *(const bf16x8*)(vpn + D_);
    kpn += 4096; vpn += 4096;

    *(bf16x8*)&Ks[0][kst0] = kreg0;
    *(bf16x8*)&Ks[0][kst1] = kreg1;
    VPACK(0)

    if (kts + 1 < kte) {
        kreg0 = *(const bf16x8*)kpn;
        kreg1 = *(const bf16x8*)(kpn + 8);
        vreg0 = *(const bf16x8*)vpn;
        vreg1 = *(const bf16x8*)(vpn + D_);
        kpn += 4096; vpn += 4096;
    }
    __syncthreads();

    for (int kt = kts; kt < kte; ++kt) {
        const int cur = (kt - kts) & 1;

        if (kt + 1 < kte) {
            *(bf16x8*)&Ks[cur ^ 1][kst0] = kreg0;
            *(bf16x8*)&Ks[cur ^ 1][kst1] = kreg1;
            VPACK(cur ^ 1)
        }
        if (kt + 2 < kte) {
            kreg0 = *(const bf16x8*)kpn;
            kreg1 = *(const bf16x8*)(kpn + 8);
            vreg0 = *(const bf16x8*)vpn;
            vreg1 = *(const bf16x8*)(vpn + D_);
            kpn += 4096; vpn += 4096;
        }

        f32x4 s[4];
        __builtin_amdgcn_s_setprio(1);
#pragma unroll
        for (int cb = 0; cb < 4; cb++) {
            const int row = cb * 16 + lr;
            bf16x8 kf0 = *(const bf16x8*)&Ks[cur][(row * 64 + lg * 8) ^ rsw];
            bf16x8 kf1 = *(const bf16x8*)&Ks[cur][(row * 64 + 32 + lg * 8) ^ rsw];
            f32x4 acc = (f32x4){0.f, 0.f, 0.f, 0.f};
            acc = __builtin_amdgcn_mfma_f32_16x16x32_bf16(kf0, qf0, acc, 0, 0, 0);
            acc = __builtin_amdgcn_mfma_f32_16x16x32_bf16(kf1, qf1, acc, 0, 0, 0);
            s[cb] = acc;
        }
        __builtin_amdgcn_s_setprio(0);

        if (kt == qt) {
#pragma unroll
            for (int cb = 0; cb < 4; cb++)
#pragma unroll
                for (int r = 0; r < 4; r++)
                    if (kt * 64 + cb * 16 + lg * 4 + r > qrow_g) s[cb][r] = -INFINITY;
        }

        float rm;
        {
            const float t0 = fmaxf(fmaxf(s[0][0], s[0][1]), fmaxf(s[0][2], s[0][3]));
            const float t1 = fmaxf(fmaxf(s[1][0], s[1][1]), fmaxf(s[1][2], s[1][3]));
            const float t2 = fmaxf(fmaxf(s[2][0], s[2][1]), fmaxf(s[2][2], s[2][3]));
            const float t3 = fmaxf(fmaxf(s[3][0], s[3][1]), fmaxf(s[3][2], s[3][3]));
            rm = fmaxf(fmaxf(t0, t1), fmaxf(t2, t3));
        }
        rm = fmaxf(rm, __shfl_xor(rm, 16));
        rm = fmaxf(rm, __shfl_xor(rm, 32));

        if (!__all(rm <= m_run + 8.0f)) {
            const float mnew = fmaxf(m_run, rm);
            const float fsc  = exp2f(m_run - mnew);
            m_run = mnew;
            l_run *= fsc;
            float fr[4];
#pragma unroll
            for (int r = 0; r < 4; r++) fr[r] = __shfl(fsc, lg * 4 + r);
#pragma unroll
            for (int db = 0; db < 4; db++)
#pragma unroll
                for (int r = 0; r < 4; r++) oacc[db][r] *= fr[r];
        }

        float p[4][4];
#pragma unroll
        for (int cb = 0; cb < 4; cb++)
#pragma unroll
            for (int r = 0; r < 4; r++)
                p[cb][r] = exp2f(s[cb][r] - m_run);
        float rs;
        {
            const float t0 = (p[0][0] + p[0][1]) + (p[0][2] + p[0][3]);
            const float t1 = (p[1][0] + p[1][1]) + (p[1][2] + p[1][3]);
            const float t2 = (p[2][0] + p[2][1]) + (p[2][2] + p[2][3]);
            const float t3 = (p[3][0] + p[3][1]) + (p[3][2] + p[3][3]);
            rs = (t0 + t1) + (t2 + t3);
        }
        rs += __shfl_xor(rs, 16);
        rs += __shfl_xor(rs, 32);
        l_run += rs;

        bf16x8 pf0, pf1;
#pragma unroll
        for (int r = 0; r < 4; r++) {
            pf0[r]     = (short)f2b(p[0][r]);
            pf0[4 + r] = (short)f2b(p[1][r]);
            pf1[r]     = (short)f2b(p[2][r]);
            pf1[4 + r] = (short)f2b(p[3][r]);
        }

        __builtin_amdgcn_s_setprio(1);
#pragma unroll
        for (int db = 0; db < 4; db++) {
            const int row = db * 16 + lr;
            bf16x8 vf0 = *(const bf16x8*)&Vt[cur][(row * 64 + lg * 8) ^ rsw];
            bf16x8 vf1 = *(const bf16x8*)&Vt[cur][(row * 64 + 32 + lg * 8) ^ rsw];
            oacc[db] = __builtin_amdgcn_mfma_f32_16x16x32_bf16(pf0, vf0, oacc[db], 0, 0, 0);
            oacc[db] = __builtin_amdgcn_mfma_f32_16x16x32_bf16(pf1, vf1, oacc[db], 0, 0, 0);
        }
        __builtin_amdgcn_s_setprio(0);

        __syncthreads();
    }
#undef VPACK

    unsigned short* Op = half ? Op1 : Op0;
#pragma unroll
    for (int r = 0; r < 4; r++) {
        const int trow = qt * 64 + wave * 16 + lg * 4 + r;
        unsigned short* op = Op + ((size_t)bh * T_ + trow) * D_;
#pragma unroll
        for (int db = 0; db < 4; db++)
            op[db * 16 + lr] = f2b(oacc[db][r]);
    }
    if (lg == 0) {
        const int trow = qt * 64 + wave * 16 + lr;
        mlbuf[(size_t)half * (B_ * H_ * T_) + (size_t)bh * T_ + trow] =
            make_float2(m_run, l_run);
    }
}

// ---------------------------------------------------------------------------
// combine partials: y = (O0*w0 + O1*w1) / (l0*w0 + l1*w1), w_i = 2^(m_i - m)
// ---------------------------------------------------------------------------
__global__ __launch_bounds__(256) void combine_kernel(
    const unsigned short* __restrict__ Op0, const unsigned short* __restrict__ Op1,
    const float2* __restrict__ mlbuf, unsigned short* __restrict__ y)
{
    const int ro = blockIdx.x * 16 + (threadIdx.x >> 4);   // 0..65535 (bh*T+t)
    const int d0 = (threadIdx.x & 15) * 4;

    const float2 ml0 = mlbuf[ro];
    const float2 ml1 = mlbuf[B_ * H_ * T_ + ro];
    const float m  = fmaxf(ml0.x, ml1.x);
    const float w0 = exp2f(ml0.x - m);
    const float w1 = exp2f(ml1.x - m);
    const float inv = 1.0f / (ml0.y * w0 + ml1.y * w1);

    const size_t off = (size_t)ro * D_ + d0;
    const ushort4 o0 = *(const ushort4*)&Op0[off];
    const ushort4 o1 = *(const ushort4*)&Op1[off];

    ushort4 res;
    res.x = f2b((b2f(o0.x) * w0 + b2f(o1.x) * w1) * inv);
    res.y = f2b((b2f(o0.y) * w0 + b2f(o1.y) * w1) * inv);
    res.z = f2b((b2f(o0.z) * w0 + b2f(o1.z) * w1) * inv);
    res.w = f2b((b2f(o0.w) * w0 + b2f(o1.w) * w1) * inv);

    const int bh = ro >> 11, t = ro & 2047;
    const int b = bh >> 4, h = bh & 15;
    *(ushort4*)&y[((size_t)(b * T_ + t) * C_) + h * D_ + d0] = res;
}

// ---------------------------------------------------------------------------
extern "C" void kernel_launch(void* const* d_in, const int* in_sizes, int n_in,
                              void* d_out, int out_size, void* d_ws, size_t ws_size,
                              hipStream_t stream)
{
    const float* x       = (const float*)d_in[0];
    const float* Wqkv    = (const float*)d_in[1];
    const float* bqkv    = (const float*)d_in[2];
    const float* Wproj   = (const float*)d_in[3];
    const float* bproj   = (const float*)d_in[4];
    const float* Wrouter = (const float*)d_in[5];
    const float* brouter = (const float*)d_in[6];
    const float* Wq_rt   = (const float*)d_in[7];
    const float* bq_rt   = (const float*)d_in[8];

    float* out = (float*)d_out;
    char*  ws  = (char*)d_ws;

    const size_t MT  = (size_t)B_ * T_;
    const size_t QKV = MT * C_;

    unsigned short* xb   = (unsigned short*)ws;
    unsigned short* Wqt  = xb  + QKV;
    unsigned short* Wpt  = Wqt + (size_t)3 * C_ * C_;
    unsigned short* q    = Wpt + (size_t)C_ * C_;
    unsigned short* k    = q + QKV;
    unsigned short* v    = k + QKV;
    unsigned short* yab  = v + QKV;
    float* cm   = (float*)(yab + QKV);
    float* qrt  = cm  + (size_t)B_ * NCH * C_;
    float* ren  = qrt + MT * RD;
    float2* mlbuf = (float2*)(ren + (size_t)B_ * NCH * RD);       // 2*65536 float2
    unsigned short* Op1 = (unsigned short*)(mlbuf + 2 * B_ * H_ * T_);  // 4Mi bf16
    unsigned short* Op0 = xb;   // xb dead after qkv GEMM — reuse as partial O

    float* y_out   = out;
    float* idx_out = out + QKV;
    float* sc_out  = idx_out + MT * TOPB;
    float* emb_out = sc_out + MT * NCH;

    // 1) fused preprocessing (W transposes, qrt, chunkmean+cast)
    prep_fused<<<2304, 256, 0, stream>>>(x, xb, Wqkv, Wqt, Wproj, Wpt,
                                         Wq_rt, bq_rt, qrt, cm);

    // 2) qkv projection
    gemm_qkv_128x256<<<dim3(384), 512, 0, stream>>>(
        xb, Wqt, bqkv, q, k, v, (int)MT, 3 * C_, C_);

    // 3) routing embeds and top-k
    embeds_kernel<<<8, 256, 0, stream>>>(cm, Wrouter, brouter, emb_out, ren);
    scores_topk<<<(int)(MT / 64), 64, 0, stream>>>(qrt, ren, sc_out, idx_out);

    // 4) split-K flash attention (partials) + combine -> bf16 yab
    attn_mfma<<<dim3(2048), 256, 0, stream>>>(q, k, v, Op0, Op1, mlbuf);
    combine_kernel<<<dim3(4096), 256, 0, stream>>>(Op0, Op1, mlbuf, yab);

    // 5) output projection (8-wave)
    gemm_proj_128<<<dim3(C_ / 128, MT / 128), 512, 0, stream>>>(
        yab, Wpt, bproj, y_out, (int)MT, C_, C_);
}

// Round 23
// 172.418 us; speedup vs baseline: 1.6977x; 1.0137x over previous
//
#include <hip/hip_runtime.h>
#include <hip/hip_bf16.h>
#include <math.h>

#define B_   2
#define T_   2048
#define C_   1024
#define H_   16
#define D_   64
#define NCH  32
#define RD   32
#define TOPB 8

typedef __attribute__((ext_vector_type(8))) short bf16x8;
typedef __attribute__((ext_vector_type(4))) float f32x4;

static __device__ __forceinline__ unsigned short f2b(float f) {
    return __bfloat16_as_ushort(__float2bfloat16(f));
}
static __device__ __forceinline__ float b2f(unsigned short u) {
    union { unsigned u32; float f; } c; c.u32 = ((unsigned)u) << 16; return c.f;
}

#define SCALE2 0.18033688f   /* 0.125 * 1.44269504 (log2 domain) */

// ---------------------------------------------------------------------------
// prep_fused v2 (2304 blocks): W transposes, qrt+l2norm, chunkmean+cast
// ---------------------------------------------------------------------------
__global__ __launch_bounds__(256) void prep_fused(
    const float* __restrict__ x, unsigned short* __restrict__ xb,
    const float* __restrict__ Wqkv, unsigned short* __restrict__ Wqt,
    const float* __restrict__ Wproj, unsigned short* __restrict__ Wpt,
    const float* __restrict__ Wq_rt, const float* __restrict__ bq_rt,
    float* __restrict__ qrt, float* __restrict__ cm)
{
    __shared__ float smem[64 * 65];
    const int bid = blockIdx.x;
    const int tid = threadIdx.x;

    if (bid < 1024) {                      // ---- weight transpose+cast
        const float* W; unsigned short* Wt; int N, local;
        if (bid < 768) { W = Wqkv;  Wt = Wqt; N = 3072; local = bid; }
        else           { W = Wproj; Wt = Wpt; N = 1024; local = bid - 768; }
        const int nblk = N >> 6;
        const int n0 = (local % nblk) * 64, k0 = (local / nblk) * 64;
        float (*t)[65] = (float(*)[65])smem;
#pragma unroll
        for (int i = 0; i < 4; i++) {
            const int f = tid + i * 256;
            const int r = f >> 4, c4 = (f & 15) * 4;
            float4 v = *(const float4*)&W[(size_t)(k0 + r) * N + n0 + c4];
            t[r][c4 + 0] = v.x; t[r][c4 + 1] = v.y;
            t[r][c4 + 2] = v.z; t[r][c4 + 3] = v.w;
        }
        __syncthreads();
#pragma unroll
        for (int i = 0; i < 2; i++) {
            const int s = tid + i * 256;
            const int rn = s >> 3, ck8 = (s & 7) * 8;
            bf16x8 o;
#pragma unroll
            for (int j = 0; j < 8; j++) o[j] = (short)f2b(t[ck8 + j][rn]);
            *(bf16x8*)&Wt[(size_t)(n0 + rn) * 1024 + k0 + ck8] = o;
        }
    } else if (bid < 2048) {               // ---- qrt projection + l2norm
        float (*part)[4][32] = (float(*)[4][32])smem;
        const int r0 = (bid - 1024) * 4;
        const int g = tid >> 5;
        const int n = tid & 31;
        const float* w  = Wq_rt + (size_t)(g * 128) * RD + n;
        const float* a0 = x + (size_t)(r0 + 0) * C_ + g * 128;
        const float* a1 = x + (size_t)(r0 + 1) * C_ + g * 128;
        const float* a2 = x + (size_t)(r0 + 2) * C_ + g * 128;
        const float* a3 = x + (size_t)(r0 + 3) * C_ + g * 128;
        float acc0 = 0.f, acc1 = 0.f, acc2 = 0.f, acc3 = 0.f;
#pragma unroll 8
        for (int i = 0; i < 128; i += 4) {
            const float w0 = w[(i + 0) * RD];
            const float w1 = w[(i + 1) * RD];
            const float w2 = w[(i + 2) * RD];
            const float w3 = w[(i + 3) * RD];
            float4 x0 = *(const float4*)&a0[i];
            float4 x1 = *(const float4*)&a1[i];
            float4 x2 = *(const float4*)&a2[i];
            float4 x3 = *(const float4*)&a3[i];
            acc0 += x0.x * w0; acc0 += x0.y * w1; acc0 += x0.z * w2; acc0 += x0.w * w3;
            acc1 += x1.x * w0; acc1 += x1.y * w1; acc1 += x1.z * w2; acc1 += x1.w * w3;
            acc2 += x2.x * w0; acc2 += x2.y * w1; acc2 += x2.z * w2; acc2 += x2.w * w3;
            acc3 += x3.x * w0; acc3 += x3.y * w1; acc3 += x3.z * w2; acc3 += x3.w * w3;
        }
        part[g][0][n] = acc0;
        part[g][1][n] = acc1;
        part[g][2][n] = acc2;
        part[g][3][n] = acc3;
        __syncthreads();
        if (g < 4) {
            float s = part[0][g][n];
#pragma unroll
            for (int gg = 1; gg < 8; gg++) s += part[gg][g][n];
            s += bq_rt[n];
            float ss = s * s;
#pragma unroll
            for (int off = 16; off >= 1; off >>= 1) ss += __shfl_xor(ss, off, 32);
            qrt[(size_t)(r0 + g) * RD + n] = s / fmaxf(sqrtf(ss), 1e-12f);
        }
    } else {                               // ---- chunk means + x->bf16 cast
        const int local = bid - 2048;      // 0..255
        const int bc = local & 63;
        const int b = bc >> 5, n = bc & 31;
        const int c = (local >> 6) * 256 + tid;
        const size_t rowbase = ((size_t)b * T_ + n * 64) * C_ + c;
        float s = 0.f;
        for (int i = 0; i < 64; i++) {
            const float v = x[rowbase + (size_t)i * C_];
            s += v;
            xb[rowbase + (size_t)i * C_] = f2b(v);
        }
        cm[(size_t)bc * C_ + c] = s * (1.0f / 64.0f);
    }
}

// ---------------------------------------------------------------------------
// routing embeds + l2norm fused
// ---------------------------------------------------------------------------
__global__ void embeds_kernel(const float* __restrict__ cm, const float* __restrict__ W,
                              const float* __restrict__ bias,
                              float* __restrict__ emb_out, float* __restrict__ ren)
{
    const int row  = blockIdx.x * 8 + (threadIdx.x >> 5);
    const int lane = threadIdx.x & 31;
    if (row >= B_ * NCH) return;
    const float* a = cm + (size_t)row * C_;
    float acc = 0.f;
    for (int k = 0; k < C_; k += 4) {
        float4 a4 = *(const float4*)&a[k];
        acc += a4.x * W[(k + 0) * RD + lane];
        acc += a4.y * W[(k + 1) * RD + lane];
        acc += a4.z * W[(k + 2) * RD + lane];
        acc += a4.w * W[(k + 3) * RD + lane];
    }
    acc += bias[lane];
    emb_out[(size_t)row * RD + lane] = acc;
    float ss = acc * acc;
#pragma unroll
    for (int off = 16; off >= 1; off >>= 1) ss += __shfl_xor(ss, off, 32);
    ren[(size_t)row * RD + lane] = acc / fmaxf(sqrtf(ss), 1e-12f);
}

// ---------------------------------------------------------------------------
// qkv GEMM, 128x256 tile, 8 waves, tri-buffered + counted vmcnt (R14)
// ---------------------------------------------------------------------------
__global__ __launch_bounds__(512, 4) void gemm_qkv_128x256(
    const unsigned short* __restrict__ A, const unsigned short* __restrict__ Bt,
    const float* __restrict__ bias,
    unsigned short* __restrict__ qp, unsigned short* __restrict__ kp,
    unsigned short* __restrict__ vp, int M, int N, int K)
{
    __shared__ unsigned short lds[3][12288];

    const int tid  = threadIdx.x;
    const int wid  = tid >> 6;
    const int lane = tid & 63;
    const int lr = lane & 15, lg = lane >> 4;
    const int wm = wid >> 2;
    const int wn = wid & 3;

    const int bid = blockIdx.x;
    const int swz = (bid & 7) * 48 + (bid >> 3);
    const int m0 = (swz & 31) << 7;
    const int n0 = (swz >> 5) << 8;

    const int srow = tid >> 2;
    const int sswz = (((srow & 3) ^ ((srow >> 2) & 3)) << 4);
    const int skel = (((tid & 3) << 4) ^ sswz) >> 1;
    const unsigned short* gA  = A  + (size_t)(m0 + srow) * K + skel;
    const unsigned short* gB0 = Bt + (size_t)(n0 + srow) * K + skel;
    const unsigned short* gB1 = Bt + (size_t)(n0 + srow + 128) * K + skel;
    const int lb = wid * 512;

#define QSTAGE(sl, kofs)                                                          \
    __builtin_amdgcn_global_load_lds(                                             \
        (const __attribute__((address_space(1))) int*)(gA + (kofs)),              \
        (__attribute__((address_space(3))) int*)&lds[sl][lb], 16, 0, 0);          \
    __builtin_amdgcn_global_load_lds(                                             \
        (const __attribute__((address_space(1))) int*)(gB0 + (kofs)),             \
        (__attribute__((address_space(3))) int*)&lds[sl][4096 + lb], 16, 0, 0);   \
    __builtin_amdgcn_global_load_lds(                                             \
        (const __attribute__((address_space(1))) int*)(gB1 + (kofs)),             \
        (__attribute__((address_space(3))) int*)&lds[sl][8192 + lb], 16, 0, 0);

    const int rswz = (((lr & 3) ^ ((lr >> 2) & 3)) << 4);
    const int acol = (((lg << 4) ^ rswz) >> 1);

    f32x4 acc[4][4];
#pragma unroll
    for (int i = 0; i < 4; i++)
#pragma unroll
        for (int j = 0; j < 4; j++) acc[i][j] = (f32x4){0.f, 0.f, 0.f, 0.f};

    const int nt = K >> 5;

    QSTAGE(0, 0)
    QSTAGE(1, 32)
    asm volatile("s_waitcnt vmcnt(3)" ::: "memory");
    __builtin_amdgcn_s_barrier();

    int cur = 0;
    for (int t = 0; t < nt; ++t) {
        int s2 = cur + 2; if (s2 >= 3) s2 -= 3;
        if (t + 2 < nt) { QSTAGE(s2, (t + 2) << 5) }

        const unsigned short* sA = &lds[cur][0];
        const unsigned short* sB = &lds[cur][4096];

        bf16x8 af[4], bfr[4];
#pragma unroll
        for (int mi = 0; mi < 4; mi++)
            af[mi] = *(const bf16x8*)&sA[(wm * 64 + mi * 16 + lr) * 32 + acol];
#pragma unroll
        for (int ni = 0; ni < 4; ni++)
            bfr[ni] = *(const bf16x8*)&sB[(wn * 64 + ni * 16 + lr) * 32 + acol];

        __builtin_amdgcn_s_setprio(1);
#pragma unroll
        for (int mi = 0; mi < 4; mi++)
#pragma unroll
            for (int ni = 0; ni < 4; ni++)
                acc[mi][ni] = __builtin_amdgcn_mfma_f32_16x16x32_bf16(
                    af[mi], bfr[ni], acc[mi][ni], 0, 0, 0);
        __builtin_amdgcn_s_setprio(0);

        if (t + 1 < nt) {
            if (t + 2 < nt) { asm volatile("s_waitcnt vmcnt(3)" ::: "memory"); }
            else            { asm volatile("s_waitcnt vmcnt(0)" ::: "memory"); }
            __builtin_amdgcn_s_barrier();
        }
        cur += 1; if (cur == 3) cur = 0;
    }
#undef QSTAGE

#pragma unroll
    for (int ni = 0; ni < 4; ni++) {
        const int col = n0 + wn * 64 + ni * 16 + lr;
        const float bv = bias[col];
        const int which = col >> 10;
        const int c  = col & 1023;
        const int hh = c >> 6;
        const int dd = c & 63;
        unsigned short* dst = (which == 0) ? qp : (which == 1) ? kp : vp;
        const float postmul = (which == 0) ? SCALE2 : 1.0f;
#pragma unroll
        for (int mi = 0; mi < 4; mi++) {
#pragma unroll
            for (int r = 0; r < 4; r++) {
                const int row = m0 + wm * 64 + mi * 16 + lg * 4 + r;
                const int bb = row >> 11, tt = row & 2047;
                dst[(((size_t)bb * H_ + hh) * T_ + tt) * D_ + dd] =
                    f2b((acc[mi][ni][r] + bv) * postmul);
            }
        }
    }
}

// ---------------------------------------------------------------------------
// proj GEMM v2: 128x128 tile, 512 threads = 8 waves (R22 proven)
// ---------------------------------------------------------------------------
__global__ __launch_bounds__(512, 1) void gemm_proj_128(
    const unsigned short* __restrict__ A, const unsigned short* __restrict__ Bt,
    const float* __restrict__ bias, float* __restrict__ out, int M, int N, int K)
{
    __shared__ unsigned short lds[3][2][4096];

    const int tid  = threadIdx.x;
    const int wid  = tid >> 6;
    const int lane = tid & 63;
    const int lr = lane & 15, lg = lane >> 4;
    const int wm = wid >> 2;
    const int wn = wid & 3;
    const int n0 = blockIdx.x * 128, m0 = blockIdx.y * 128;

    const int srow = tid >> 2;
    const int sswz = (((srow & 3) ^ ((srow >> 2) & 3)) << 4);
    const int skel = (((tid & 3) << 4) ^ sswz) >> 1;
    const unsigned short* gA = A  + (size_t)(m0 + srow) * K + skel;
    const unsigned short* gB = Bt + (size_t)(n0 + srow) * K + skel;
    const int lb = wid * 512;

#define PSTAGE(sl, kofs)                                                          \
    __builtin_amdgcn_global_load_lds(                                             \
        (const __attribute__((address_space(1))) int*)(gA + (kofs)),              \
        (__attribute__((address_space(3))) int*)&lds[sl][0][lb], 16, 0, 0);       \
    __builtin_amdgcn_global_load_lds(                                             \
        (const __attribute__((address_space(1))) int*)(gB + (kofs)),              \
        (__attribute__((address_space(3))) int*)&lds[sl][1][lb], 16, 0, 0);

    const int rswz = (((lr & 3) ^ ((lr >> 2) & 3)) << 4);
    const int acol = (((lg << 4) ^ rswz) >> 1);

    f32x4 acc[4][2];
#pragma unroll
    for (int i = 0; i < 4; i++)
#pragma unroll
        for (int j = 0; j < 2; j++) acc[i][j] = (f32x4){0.f, 0.f, 0.f, 0.f};

    const int nt = K >> 5;

    PSTAGE(0, 0)
    PSTAGE(1, 32)
    asm volatile("s_waitcnt vmcnt(2)" ::: "memory");
    __builtin_amdgcn_s_barrier();

    int cur = 0;
    for (int t = 0; t < nt; ++t) {
        int s2 = cur + 2; if (s2 >= 3) s2 -= 3;
        if (t + 2 < nt) { PSTAGE(s2, (t + 2) << 5) }

        const unsigned short* sA = &lds[cur][0][0];
        const unsigned short* sB = &lds[cur][1][0];

        bf16x8 af[4], bfr[2];
#pragma unroll
        for (int mi = 0; mi < 4; mi++)
            af[mi] = *(const bf16x8*)&sA[(wm * 64 + mi * 16 + lr) * 32 + acol];
#pragma unroll
        for (int ni = 0; ni < 2; ni++)
            bfr[ni] = *(const bf16x8*)&sB[(wn * 32 + ni * 16 + lr) * 32 + acol];

        __builtin_amdgcn_s_setprio(1);
#pragma unroll
        for (int mi = 0; mi < 4; mi++)
#pragma unroll
            for (int ni = 0; ni < 2; ni++)
                acc[mi][ni] = __builtin_amdgcn_mfma_f32_16x16x32_bf16(
                    af[mi], bfr[ni], acc[mi][ni], 0, 0, 0);
        __builtin_amdgcn_s_setprio(0);

        if (t + 1 < nt) {
            if (t + 2 < nt) { asm volatile("s_waitcnt vmcnt(2)" ::: "memory"); }
            else            { asm volatile("s_waitcnt vmcnt(0)" ::: "memory"); }
            __builtin_amdgcn_s_barrier();
        }
        cur += 1; if (cur == 3) cur = 0;
    }
#undef PSTAGE

#pragma unroll
    for (int ni = 0; ni < 2; ni++) {
        const int col = n0 + wn * 32 + ni * 16 + lr;
        const float bv = bias[col];
#pragma unroll
        for (int mi = 0; mi < 4; mi++) {
#pragma unroll
            for (int r = 0; r < 4; r++) {
                const int row = m0 + wm * 64 + mi * 16 + lg * 4 + r;
                out[(size_t)row * N + col] = acc[mi][ni][r] + bv;
            }
        }
    }
}

// ---------------------------------------------------------------------------
// routing scores + top-8
// ---------------------------------------------------------------------------
__global__ void scores_topk(const float* __restrict__ qrt, const float* __restrict__ ren,
                            float* __restrict__ sc_out, float* __restrict__ idx_out)
{
    const int row = blockIdx.x * 64 + threadIdx.x;
    if (row >= B_ * T_) return;
    const int b = row / T_;
    float q[RD];
#pragma unroll
    for (int i = 0; i < RD; i++) q[i] = qrt[(size_t)row * RD + i];
    const float* rb = ren + (size_t)b * NCH * RD;
    float s[NCH];
#pragma unroll 4
    for (int n = 0; n < NCH; n++) {
        float acc = 0.f;
#pragma unroll
        for (int i = 0; i < RD; i++) acc += q[i] * rb[n * RD + i];
        s[n] = acc;
        sc_out[(size_t)row * NCH + n] = acc;
    }
    unsigned mask = 0;
    for (int t = 0; t < TOPB; t++) {
        float best = -INFINITY;
        int bi = 0;
#pragma unroll
        for (int n = 0; n < NCH; n++) {
            const bool ok = !((mask >> n) & 1u) && (s[n] > best);
            if (ok) { best = s[n]; bi = n; }
        }
        mask |= (1u << bi);
        idx_out[(size_t)row * TOPB + t] = (float)bi;
    }
}

// ---------------------------------------------------------------------------
// MFMA bf16 flash attention v13: split-K(2), K double-buffered, V SINGLE-
// buffered (24 KB LDS -> 6 blocks/CU, was 5). V(kt+1) written after PV(kt)
// between two barriers; K dbuf unchanged (write at iter top, 0 extra cost).
// VGPR budget unchanged (no launch_bounds force — R20 lesson).
// ---------------------------------------------------------------------------
#define SW(row, idx) ((idx) ^ (((row) & 7) << 3))

__global__ __launch_bounds__(256) void attn_mfma(
    const unsigned short* __restrict__ qg, const unsigned short* __restrict__ kg,
    const unsigned short* __restrict__ vg,
    unsigned short* __restrict__ Op0, unsigned short* __restrict__ Op1,
    float2* __restrict__ mlbuf)
{
    const int bid  = blockIdx.x;              // 0..2047
    const int xcd  = bid & 7;
    const int h    = xcd + 8 * ((bid >> 3) & 1);
    const int b    = (bid >> 4) & 1;
    const int rest = bid >> 5;                // 0..63
    const int half = rest & 1;
    const int i    = rest >> 1;               // 0..31
    const int qt   = 31 - i;                  // long blocks first

    const int tid  = threadIdx.x;
    const int wave = tid >> 6;
    const int lane = tid & 63;
    const int lg = lane >> 4;
    const int lr = lane & 15;

    const int bh = b * H_ + h;

    const int ntt = qt + 1;
    const int nh0 = (ntt + 1) >> 1;
    const int kts = half ? nh0 : 0;
    const int kte = half ? ntt : nh0;

    float m_run = -INFINITY, l_run = 0.f;

    if (kts >= kte) {
        if (lg == 0 && wave < 4) {
            const int trow = qt * 64 + wave * 16 + lr;
            mlbuf[(size_t)half * (B_ * H_ * T_) + (size_t)bh * T_ + trow] =
                make_float2(-INFINITY, 0.f);
        }
        return;
    }

    __shared__ short Ks[2][64 * 64];
    __shared__ short Vt[64 * 64];        // single-buffered

    const size_t base = ((size_t)bh * T_) * D_;

    bf16x8 qf0, qf1;
    {
        const short* qp = (const short*)qg + base + (size_t)(qt * 64 + wave * 16 + lr) * D_;
        qf0 = *(const bf16x8*)&qp[lg * 8];
        qf1 = *(const bf16x8*)&qp[32 + lg * 8];
    }

    const int srr = tid >> 2;
    const int sc0 = (tid & 3) * 16;
    const int vrp = tid & 31;
    const int vcg = tid >> 5;
    const int kv0   = 2 * vrp;
    const int vslot = ((kv0 >> 5) << 5) + (((kv0 >> 2) & 3) << 3) +
                      (((kv0 >> 4) & 1) << 2) + (kv0 & 3);

    const int kst0 = SW(srr, srr * 64 + sc0);
    const int kst1 = SW(srr, srr * 64 + sc0 + 8);
    const int rsw = (lr & 7) << 3;

    bf16x8 kreg0, kreg1, vreg0, vreg1;

    f32x4 oacc[4];
#pragma unroll
    for (int r = 0; r < 4; r++) oacc[r] = (f32x4){0.f, 0.f, 0.f, 0.f};
    const int qrow_g = qt * 64 + wave * 16 + lr;

#define VPACK()                                                                 \
    {                                                                           \
        const unsigned* v0d = (const unsigned*)&vreg0;                          \
        const unsigned* v1d = (const unsigned*)&vreg1;                          \
        _Pragma("unroll")                                                       \
        for (int jj = 0; jj < 8; jj++) {                                        \
            const unsigned sel = (jj & 1) ? 0x07060302u : 0x05040100u;          \
            const unsigned dw = __builtin_amdgcn_perm(v1d[jj >> 1], v0d[jj >> 1], sel); \
            *(unsigned*)&Vt[SW(jj, (vcg * 8 + jj) * 64 + vslot)] = dw;          \
        }                                                                       \
    }

    const short* kpn = (const short*)kg + base + (size_t)(kts * 64 + srr) * D_ + sc0;
    const short* vpn = (const short*)vg + base + (size_t)(kts * 64 + kv0) * D_ + vcg * 8;

    // prologue: tile kts into LDS; prefetch kts+1 into regs
    kreg0 = *(const bf16x8*)kpn;
    kreg1 = *(const bf16x8*)(kpn + 8);
    vreg0 = *(const bf16x8*)vpn;
    vreg1 = *(const bf16x8*)(vpn + D_);
    kpn += 4096; vpn += 4096;

    *(bf16x8*)&Ks[0][kst0] = kreg0;
    *(bf16x8*)&Ks[0][kst1] = kreg1;
    VPACK()

    if (kts + 1 < kte) {
        kreg0 = *(const bf16x8*)kpn;
        kreg1 = *(const bf16x8*)(kpn + 8);
        vreg0 = *(const bf16x8*)vpn;
        vreg1 = *(const bf16x8*)(vpn + D_);
        kpn += 4096; vpn += 4096;
    }
    __syncthreads();

    for (int kt = kts; kt < kte; ++kt) {
        const int cur = (kt - kts) & 1;

        // write next K into the other K buffer (its readers finished last iter)
        if (kt + 1 < kte) {
            *(bf16x8*)&Ks[cur ^ 1][kst0] = kreg0;
            *(bf16x8*)&Ks[cur ^ 1][kst1] = kreg1;
        }

        // QK^T from Ks[cur]
        f32x4 s[4];
        __builtin_amdgcn_s_setprio(1);
#pragma unroll
        for (int cb = 0; cb < 4; cb++) {
            const int row = cb * 16 + lr;
            bf16x8 kf0 = *(const bf16x8*)&Ks[cur][(row * 64 + lg * 8) ^ rsw];
            bf16x8 kf1 = *(const bf16x8*)&Ks[cur][(row * 64 + 32 + lg * 8) ^ rsw];
            f32x4 acc = (f32x4){0.f, 0.f, 0.f, 0.f};
            acc = __builtin_amdgcn_mfma_f32_16x16x32_bf16(kf0, qf0, acc, 0, 0, 0);
            acc = __builtin_amdgcn_mfma_f32_16x16x32_bf16(kf1, qf1, acc, 0, 0, 0);
            s[cb] = acc;
        }
        __builtin_amdgcn_s_setprio(0);

        if (kt == qt) {
#pragma unroll
            for (int cb = 0; cb < 4; cb++)
#pragma unroll
                for (int r = 0; r < 4; r++)
                    if (kt * 64 + cb * 16 + lg * 4 + r > qrow_g) s[cb][r] = -INFINITY;
        }

        float rm;
        {
            const float t0 = fmaxf(fmaxf(s[0][0], s[0][1]), fmaxf(s[0][2], s[0][3]));
            const float t1 = fmaxf(fmaxf(s[1][0], s[1][1]), fmaxf(s[1][2], s[1][3]));
            const float t2 = fmaxf(fmaxf(s[2][0], s[2][1]), fmaxf(s[2][2], s[2][3]));
            const float t3 = fmaxf(fmaxf(s[3][0], s[3][1]), fmaxf(s[3][2], s[3][3]));
            rm = fmaxf(fmaxf(t0, t1), fmaxf(t2, t3));
        }
        rm = fmaxf(rm, __shfl_xor(rm, 16));
        rm = fmaxf(rm, __shfl_xor(rm, 32));

        if (!__all(rm <= m_run + 8.0f)) {
            const float mnew = fmaxf(m_run, rm);
            const float fsc  = exp2f(m_run - mnew);
            m_run = mnew;
            l_run *= fsc;
            float fr[4];
#pragma unroll
            for (int r = 0; r < 4; r++) fr[r] = __shfl(fsc, lg * 4 + r);
#pragma unroll
            for (int db = 0; db < 4; db++)
#pragma unroll
                for (int r = 0; r < 4; r++) oacc[db][r] *= fr[r];
        }

        float p[4][4];
#pragma unroll
        for (int cb = 0; cb < 4; cb++)
#pragma unroll
            for (int r = 0; r < 4; r++)
                p[cb][r] = exp2f(s[cb][r] - m_run);
        float rs;
        {
            const float t0 = (p[0][0] + p[0][1]) + (p[0][2] + p[0][3]);
            const float t1 = (p[1][0] + p[1][1]) + (p[1][2] + p[1][3]);
            const float t2 = (p[2][0] + p[2][1]) + (p[2][2] + p[2][3]);
            const float t3 = (p[3][0] + p[3][1]) + (p[3][2] + p[3][3]);
            rs = (t0 + t1) + (t2 + t3);
        }
        rs += __shfl_xor(rs, 16);
        rs += __shfl_xor(rs, 32);
        l_run += rs;

        bf16x8 pf0, pf1;
#pragma unroll
        for (int r = 0; r < 4; r++) {
            pf0[r]     = (short)f2b(p[0][r]);
            pf0[4 + r] = (short)f2b(p[1][r]);
            pf1[r]     = (short)f2b(p[2][r]);
            pf1[4 + r] = (short)f2b(p[3][r]);
        }

        // PV from the single V buffer (holds V(kt))
        __builtin_amdgcn_s_setprio(1);
#pragma unroll
        for (int db = 0; db < 4; db++) {
            const int row = db * 16 + lr;
            bf16x8 vf0 = *(const bf16x8*)&Vt[(row * 64 + lg * 8) ^ rsw];
            bf16x8 vf1 = *(const bf16x8*)&Vt[(row * 64 + 32 + lg * 8) ^ rsw];
            oacc[db] = __builtin_amdgcn_mfma_f32_16x16x32_bf16(pf0, vf0, oacc[db], 0, 0, 0);
            oacc[db] = __builtin_amdgcn_mfma_f32_16x16x32_bf16(pf1, vf1, oacc[db], 0, 0, 0);
        }
        __builtin_amdgcn_s_setprio(0);

        // V rotation: PV(kt) reads done -> write V(kt+1) -> visible
        if (kt + 1 < kte) {
            __syncthreads();                 // all waves finished PV(kt) + K writes
            VPACK()                          // V(kt+1) from regs
            if (kt + 2 < kte) {              // prefetch tile kt+2
                kreg0 = *(const bf16x8*)kpn;
                kreg1 = *(const bf16x8*)(kpn + 8);
                vreg0 = *(const bf16x8*)vpn;
                vreg1 = *(const bf16x8*)(vpn + D_);
                kpn += 4096; vpn += 4096;
            }
            __syncthreads();                 // V(kt+1) + K(kt+1) visible
        }
    }
#undef VPACK

    unsigned short* Op = half ? Op1 : Op0;
#pragma unroll
    for (int r = 0; r < 4; r++) {
        const int trow = qt * 64 + wave * 16 + lg * 4 + r;
        unsigned short* op = Op + ((size_t)bh * T_ + trow) * D_;
#pragma unroll
        for (int db = 0; db < 4; db++)
            op[db * 16 + lr] = f2b(oacc[db][r]);
    }
    if (lg == 0) {
        const int trow = qt * 64 + wave * 16 + lr;
        mlbuf[(size_t)half * (B_ * H_ * T_) + (size_t)bh * T_ + trow] =
            make_float2(m_run, l_run);
    }
}

// ---------------------------------------------------------------------------
// combine partials: y = (O0*w0 + O1*w1) / (l0*w0 + l1*w1), w_i = 2^(m_i - m)
// ---------------------------------------------------------------------------
__global__ __launch_bounds__(256) void combine_kernel(
    const unsigned short* __restrict__ Op0, const unsigned short* __restrict__ Op1,
    const float2* __restrict__ mlbuf, unsigned short* __restrict__ y)
{
    const int ro = blockIdx.x * 16 + (threadIdx.x >> 4);   // 0..65535 (bh*T+t)
    const int d0 = (threadIdx.x & 15) * 4;

    const float2 ml0 = mlbuf[ro];
    const float2 ml1 = mlbuf[B_ * H_ * T_ + ro];
    const float m  = fmaxf(ml0.x, ml1.x);
    const float w0 = exp2f(ml0.x - m);
    const float w1 = exp2f(ml1.x - m);
    const float inv = 1.0f / (ml0.y * w0 + ml1.y * w1);

    const size_t off = (size_t)ro * D_ + d0;
    const ushort4 o0 = *(const ushort4*)&Op0[off];
    const ushort4 o1 = *(const ushort4*)&Op1[off];

    ushort4 res;
    res.x = f2b((b2f(o0.x) * w0 + b2f(o1.x) * w1) * inv);
    res.y = f2b((b2f(o0.y) * w0 + b2f(o1.y) * w1) * inv);
    res.z = f2b((b2f(o0.z) * w0 + b2f(o1.z) * w1) * inv);
    res.w = f2b((b2f(o0.w) * w0 + b2f(o1.w) * w1) * inv);

    const int bh = ro >> 11, t = ro & 2047;
    const int b = bh >> 4, h = bh & 15;
    *(ushort4*)&y[((size_t)(b * T_ + t) * C_) + h * D_ + d0] = res;
}

// ---------------------------------------------------------------------------
extern "C" void kernel_launch(void* const* d_in, const int* in_sizes, int n_in,
                              void* d_out, int out_size, void* d_ws, size_t ws_size,
                              hipStream_t stream)
{
    const float* x       = (const float*)d_in[0];
    const float* Wqkv    = (const float*)d_in[1];
    const float* bqkv    = (const float*)d_in[2];
    const float* Wproj   = (const float*)d_in[3];
    const float* bproj   = (const float*)d_in[4];
    const float* Wrouter = (const float*)d_in[5];
    const float* brouter = (const float*)d_in[6];
    const float* Wq_rt   = (const float*)d_in[7];
    const float* bq_rt   = (const float*)d_in[8];

    float* out = (float*)d_out;
    char*  ws  = (char*)d_ws;

    const size_t MT  = (size_t)B_ * T_;
    const size_t QKV = MT * C_;

    unsigned short* xb   = (unsigned short*)ws;
    unsigned short* Wqt  = xb  + QKV;
    unsigned short* Wpt  = Wqt + (size_t)3 * C_ * C_;
    unsigned short* q    = Wpt + (size_t)C_ * C_;
    unsigned short* k    = q + QKV;
    unsigned short* v    = k + QKV;
    unsigned short* yab  = v + QKV;
    float* cm   = (float*)(yab + QKV);
    float* qrt  = cm  + (size_t)B_ * NCH * C_;
    float* ren  = qrt + MT * RD;
    float2* mlbuf = (float2*)(ren + (size_t)B_ * NCH * RD);       // 2*65536 float2
    unsigned short* Op1 = (unsigned short*)(mlbuf + 2 * B_ * H_ * T_);  // 4Mi bf16
    unsigned short* Op0 = xb;   // xb dead after qkv GEMM — reuse as partial O

    float* y_out   = out;
    float* idx_out = out + QKV;
    float* sc_out  = idx_out + MT * TOPB;
    float* emb_out = sc_out + MT * NCH;

    // 1) fused preprocessing (W transposes, qrt, chunkmean+cast)
    prep_fused<<<2304, 256, 0, stream>>>(x, xb, Wqkv, Wqt, Wproj, Wpt,
                                         Wq_rt, bq_rt, qrt, cm);

    // 2) qkv projection
    gemm_qkv_128x256<<<dim3(384), 512, 0, stream>>>(
        xb, Wqt, bqkv, q, k, v, (int)MT, 3 * C_, C_);

    // 3) routing embeds and top-k
    embeds_kernel<<<8, 256, 0, stream>>>(cm, Wrouter, brouter, emb_out, ren);
    scores_topk<<<(int)(MT / 64), 64, 0, stream>>>(qrt, ren, sc_out, idx_out);

    // 4) split-K flash attention (K dbuf + V single, 6 blocks/CU) + combine
    attn_mfma<<<dim3(2048), 256, 0, stream>>>(q, k, v, Op0, Op1, mlbuf);
    combine_kernel<<<dim3(4096), 256, 0, stream>>>(Op0, Op1, mlbuf, yab);

    // 5) output projection (8-wave)
    gemm_proj_128<<<dim3(C_ / 128, MT / 128), 512, 0, stream>>>(
        yab, Wpt, bproj, y_out, (int)MT, C_, C_);
}